// Round 1
// baseline (1164.883 us; speedup 1.0000x reference)
//
#include <hip/hip_runtime.h>
#include <math.h>

#define CC 128
#define HH 4
#define LL 3
#define LNEPS 1e-5f
#define GR 32
#define KC 64

typedef unsigned int u32;

__device__ __forceinline__ u32 fenc(float f){ u32 u=__float_as_uint(f); return (u&0x80000000u)? ~u : (u|0x80000000u); }
__device__ __forceinline__ float fdec(u32 u){ return (u&0x80000000u)? __uint_as_float(u&0x7FFFFFFFu) : __uint_as_float(~u); }

// ---------------- tiny precompute kernels ----------------

// out[l][k][h] = sum_c W[l][k][h*C+c] * att[l][h][c]
__global__ void k_att_collapse(const float* __restrict__ W, const float* __restrict__ att, float* __restrict__ out){
  int idx = blockIdx.x*blockDim.x + threadIdx.x;
  if(idx >= LL*CC*HH) return;
  int h = idx % HH; int k = (idx/HH)%CC; int l = idx/(HH*CC);
  const float* w = W + ((size_t)(l*CC+k))*(HH*CC) + h*CC;
  const float* a = att + (size_t)(l*HH+h)*CC;
  float s=0.f;
  for(int c=0;c<CC;c++) s += w[c]*a[c];
  out[idx] = s;
}

// We[k][c] = sum_m w_ee[k][m]*w_ep[m][c]   (k<4)
__global__ void k_We(const float* __restrict__ w_ee, const float* __restrict__ w_ep, float* __restrict__ We){
  int idx = blockIdx.x*blockDim.x + threadIdx.x;
  if(idx >= 4*CC) return;
  int c = idx & (CC-1); int k = idx >> 7;
  float s=0.f;
  for(int m=0;m<CC;m++) s += w_ee[k*CC+m]*w_ep[m*CC+c];
  We[idx]=s;
}

__global__ void k_be_vemb(const float* __restrict__ b_ee, const float* __restrict__ w_ep, const float* __restrict__ b_ep,
                          const float* __restrict__ vnf, const float* __restrict__ w_vnf, const float* __restrict__ b_vnf,
                          float* __restrict__ be, float* __restrict__ vemb){
  int t = threadIdx.x;
  if(t<CC){
    float s=b_ep[t];
    for(int m=0;m<CC;m++) s += b_ee[m]*w_ep[m*CC+t];
    be[t]=s;
  } else if(t<2*CC){
    int c=t-CC;
    float s=b_vnf[c];
    for(int j=0;j<6;j++) s += vnf[j]*w_vnf[j*CC+c];
    vemb[c]=s;
  }
}

// Wh1[k][c] = sum_m We[k][m]*attn_w1[m][c]; bh1[c] = be@w1 + vemb@w1[128:] + b1
__global__ void k_h1eff(const float* __restrict__ We, const float* __restrict__ be, const float* __restrict__ vemb,
                        const float* __restrict__ w1, const float* __restrict__ b1,
                        float* __restrict__ Wh1, float* __restrict__ bh1){
  int idx = blockIdx.x*blockDim.x + threadIdx.x;
  if(idx < 4*CC){
    int c = idx & (CC-1); int k = idx>>7;
    float s=0.f;
    for(int m=0;m<CC;m++) s += We[k*CC+m]*w1[m*CC+c];
    Wh1[idx]=s;
  } else if(idx < 5*CC){
    int c = idx - 4*CC;
    float s=b1[c];
    for(int m=0;m<CC;m++) s += be[m]*w1[m*CC+c];
    for(int j=0;j<CC;j++) s += vemb[j]*w1[(CC+j)*CC+c];
    bh1[c]=s;
  }
}

// aelin[l][k][h] (k<4), aebias[l][h]
__global__ void k_aelin(const float* __restrict__ We, const float* __restrict__ be, const float* __restrict__ wattE,
                        float* __restrict__ aelin, float* __restrict__ aebias){
  int t = threadIdx.x;
  if(t<48){
    int l=t>>4, k=(t>>2)&3, h=t&3;
    float s=0.f;
    for(int m=0;m<CC;m++) s += We[k*CC+m]*wattE[(size_t)(l*CC+m)*HH+h];
    aelin[t]=s;
  } else if(t<60){
    int i=t-48; int l=i>>2, h=i&3;
    float s=0.f;
    for(int m=0;m<CC;m++) s += be[m]*wattE[(size_t)(l*CC+m)*HH+h];
    aebias[i]=s;
  }
}

// Wbig[l][h*128+k][c] = gat_w[l][k][h*128+c] * 0.25 (head-mean folded)
__global__ void k_wbig(const float* __restrict__ gat_w, float* __restrict__ Wbig){
  int idx = blockIdx.x*blockDim.x + threadIdx.x;
  if(idx >= LL*HH*CC*CC) return;
  int c = idx & (CC-1);
  int hk = (idx>>7) & 511;
  int l = idx >> 16;
  int h = hk >> 7; int k = hk & 127;
  Wbig[idx] = gat_w[((size_t)(l*CC+k))*(HH*CC) + h*CC + c] * 0.25f;
}

__global__ void k_vvec(const float* __restrict__ vnf, const float* __restrict__ w1, const float* __restrict__ b1,
                       const float* __restrict__ w2, const float* __restrict__ b2, float* __restrict__ v){
  __shared__ float hv[CC];
  int t=threadIdx.x;
  float s=b1[t];
  for(int j=0;j<6;j++) s += vnf[j]*w1[j*CC+t];
  hv[t]=fmaxf(s,0.f);
  __syncthreads();
  float o=b2[t];
  for(int j=0;j<CC;j++) o += hv[j]*w2[j*CC+t];
  v[t]=o;
}

// ---------------- node embedding ----------------
__global__ void k_node_embed(const float* __restrict__ x, const float* __restrict__ w, const float* __restrict__ b,
                             float* __restrict__ xh, int N){
  int idx=blockIdx.x*blockDim.x+threadIdx.x;
  if(idx>=N*CC) return;
  int c=idx&(CC-1); int n=idx>>7;
  const float* xr = x+(size_t)n*8;
  float s=b[c];
  #pragma unroll
  for(int k=0;k<8;k++) s += xr[k]*w[k*CC+c];
  xh[idx]=s;
}

// ---------------- CSR by dst ----------------
__global__ void k_count(const int* __restrict__ dst, int* __restrict__ counts, int E){
  int e=blockIdx.x*blockDim.x+threadIdx.x;
  if(e<E) atomicAdd(&counts[dst[e]],1);
}

__global__ __launch_bounds__(1024) void k_scan(const int* __restrict__ counts, int* __restrict__ offsets, int N){
  __shared__ int sv[1024];
  int t=threadIdx.x;
  int per=(N+1023)/1024;
  int b=t*per; int e=b+per; if(e>N)e=N; if(b>N)b=N;
  int ssum=0;
  for(int i=b;i<e;i++) ssum+=counts[i];
  sv[t]=ssum;
  __syncthreads();
  for(int off=1;off<1024;off<<=1){
    int add = (t>=off)? sv[t-off]:0;
    __syncthreads();
    sv[t]+=add;
    __syncthreads();
  }
  int run = sv[t]-ssum;
  for(int i=b;i<e;i++){ offsets[i]=run; run+=counts[i]; }
  if(t==1023) offsets[N]=sv[1023];
}

__global__ void k_fill(const int* __restrict__ dst, const int* __restrict__ offsets, int* __restrict__ cursor,
                       int* __restrict__ elist, int E){
  int e=blockIdx.x*blockDim.x+threadIdx.x;
  if(e<E){ int d=dst[e]; int pos=atomicAdd(&cursor[d],1); elist[offsets[d]+pos]=e; }
}

// ---------------- fused edge-attention MLP -> a_e[l][e][h] ----------------
__global__ __launch_bounds__(256) void k_edge_attn(
    const float* __restrict__ edge_attr,
    const float* __restrict__ Wh1, const float* __restrict__ bh1,
    const float* __restrict__ attn_w2, const float* __restrict__ attn_b2,
    const float* __restrict__ attn_w3, const float* __restrict__ attn_b3,
    const float* __restrict__ aelin, const float* __restrict__ aebias,
    float* __restrict__ a_e, int E)
{
  __shared__ float s_w2[CC*64];
  __shared__ float s_wh1[4*CC];
  __shared__ float s_bh1[CC];
  __shared__ float s_b2[64];
  __shared__ float s_w3[64];
  __shared__ float s_lin[48];
  __shared__ float s_lbias[12];
  __shared__ float s_h1[4][CC];
  int t = threadIdx.x;
  for(int i=t;i<CC*64;i+=256) s_w2[i]=attn_w2[i];
  for(int i=t;i<4*CC;i+=256) s_wh1[i]=Wh1[i];
  if(t<CC) s_bh1[t]=bh1[t];
  if(t<64) s_b2[t]=attn_b2[t];
  if(t>=64&&t<128) s_w3[t-64]=attn_w3[t-64];
  if(t>=128&&t<176) s_lin[t-128]=aelin[t-128];
  if(t>=176&&t<188) s_lbias[t-176]=aebias[t-176];
  float b3v = attn_b3[0];
  __syncthreads();
  int wave=t>>6, lane=t&63;
  int gw = blockIdx.x*4+wave;
  int nw = gridDim.x*4;
  int iters = (E+nw-1)/nw;
  for(int it=0;it<iters;++it){
    int e = gw + it*nw;
    bool act = e < E;
    float ea0=0.f,ea1=0.f,ea2=0.f,ea3=0.f;
    if(act){ float4 v = *(const float4*)&edge_attr[(size_t)e*4]; ea0=v.x;ea1=v.y;ea2=v.z;ea3=v.w; }
    int c2 = lane+64;
    float h1a = s_bh1[lane] + ea0*s_wh1[0*CC+lane]+ea1*s_wh1[1*CC+lane]+ea2*s_wh1[2*CC+lane]+ea3*s_wh1[3*CC+lane];
    float h1b = s_bh1[c2]   + ea0*s_wh1[0*CC+c2]  +ea1*s_wh1[1*CC+c2]  +ea2*s_wh1[2*CC+c2]  +ea3*s_wh1[3*CC+c2];
    s_h1[wave][lane]=fmaxf(h1a,0.f);
    s_h1[wave][c2]=fmaxf(h1b,0.f);
    __syncthreads();
    float acc = s_b2[lane];
    #pragma unroll 8
    for(int k=0;k<CC;k++) acc += s_h1[wave][k]*s_w2[k*64+lane];
    float p = fmaxf(acc,0.f) * s_w3[lane];
    #pragma unroll
    for(int o=32;o>=1;o>>=1) p += __shfl_xor(p,o);
    float att = 1.f/(1.f+expf(-(p+b3v)));
    if(act && lane<12){
      int l = lane>>2, h = lane&3;
      float v = ea0*s_lin[(l*4+0)*4+h]+ea1*s_lin[(l*4+1)*4+h]+ea2*s_lin[(l*4+2)*4+h]+ea3*s_lin[(l*4+3)*4+h]
               + s_lbias[l*4+h];
      a_e[((size_t)l*E+e)*4+h] = att*v;
    }
    __syncthreads();
  }
}

// ---------------- per-node attention logits ----------------
__global__ void k_node_ad(const float* __restrict__ xh, const float* __restrict__ wS, const float* __restrict__ wD,
                          float* __restrict__ asrc, float* __restrict__ adst, int N){
  int idx = blockIdx.x*blockDim.x + threadIdx.x;
  if(idx >= N*8) return;
  int o = idx & 7; int n = idx >> 3;
  const float* w = ((o<4)? wS : wD) + (o&3);
  const float* xr = xh + (size_t)n*CC;
  float s=0.f;
  for(int k=0;k<CC;k++) s += xr[k]*w[(size_t)k*HH];
  ((o<4)? asrc : adst)[n*4+(o&3)] = s;
}

// ---------------- per-dst GAT aggregation (wave per node, no atomics) ----------------
__global__ __launch_bounds__(256) void k_aggregate(
    const float* __restrict__ xh, const int* __restrict__ srcArr,
    const float* __restrict__ aeL, const float* __restrict__ asrc, const float* __restrict__ adst,
    const int* __restrict__ offsets, const int* __restrict__ elist,
    float* __restrict__ sOut, int N)
{
  int wave = threadIdx.x>>6, lane = threadIdx.x&63;
  int n = blockIdx.x*4+wave;
  if(n>=N) return;
  int beg = offsets[n];
  int deg = offsets[n+1]-beg;
  const float4* ae4 = (const float4*)aeL;
  const float4* as4 = (const float4*)asrc;
  float4 ad = ((const float4*)adst)[n];
  float mx0=-1e30f,mx1=-1e30f,mx2=-1e30f,mx3=-1e30f;
  for(int base=0;base<deg;base+=64){
    int i=base+lane;
    if(i<deg){
      int e = elist[beg+i];
      float4 ae = ae4[e];
      float4 as = as4[srcArr[e]];
      float a0=as.x+ad.x+ae.x; a0=(a0>0.f)?a0:0.2f*a0;
      float a1=as.y+ad.y+ae.y; a1=(a1>0.f)?a1:0.2f*a1;
      float a2=as.z+ad.z+ae.z; a2=(a2>0.f)?a2:0.2f*a2;
      float a3=as.w+ad.w+ae.w; a3=(a3>0.f)?a3:0.2f*a3;
      mx0=fmaxf(mx0,a0); mx1=fmaxf(mx1,a1); mx2=fmaxf(mx2,a2); mx3=fmaxf(mx3,a3);
    }
  }
  #pragma unroll
  for(int o=32;o>=1;o>>=1){
    mx0=fmaxf(mx0,__shfl_xor(mx0,o));
    mx1=fmaxf(mx1,__shfl_xor(mx1,o));
    mx2=fmaxf(mx2,__shfl_xor(mx2,o));
    mx3=fmaxf(mx3,__shfl_xor(mx3,o));
  }
  float sm0=0,sm1=0,sm2=0,sm3=0;
  float acc0=0,acc1=0,acc2=0,acc3=0,acc4=0,acc5=0,acc6=0,acc7=0;
  for(int base=0;base<deg;base+=64){
    int i=base+lane;
    float ex0=0,ex1=0,ex2=0,ex3=0; int mysrc=0;
    if(i<deg){
      int e = elist[beg+i];
      mysrc = srcArr[e];
      float4 ae = ae4[e];
      float4 as = as4[mysrc];
      float a0=as.x+ad.x+ae.x; a0=(a0>0.f)?a0:0.2f*a0;
      float a1=as.y+ad.y+ae.y; a1=(a1>0.f)?a1:0.2f*a1;
      float a2=as.z+ad.z+ae.z; a2=(a2>0.f)?a2:0.2f*a2;
      float a3=as.w+ad.w+ae.w; a3=(a3>0.f)?a3:0.2f*a3;
      ex0=expf(a0-mx0); ex1=expf(a1-mx1); ex2=expf(a2-mx2); ex3=expf(a3-mx3);
      sm0+=ex0; sm1+=ex1; sm2+=ex2; sm3+=ex3;
    }
    int cnt = deg-base; if(cnt>64) cnt=64;
    for(int j=0;j<cnt;j++){
      int sr = __shfl(mysrc,j);
      float al0=__shfl(ex0,j), al1=__shfl(ex1,j), al2=__shfl(ex2,j), al3=__shfl(ex3,j);
      const float* xr = xh + (size_t)sr*CC;
      float x0 = xr[lane], x1 = xr[lane+64];
      acc0 += al0*x0; acc1 += al0*x1;
      acc2 += al1*x0; acc3 += al1*x1;
      acc4 += al2*x0; acc5 += al2*x1;
      acc6 += al3*x0; acc7 += al3*x1;
    }
  }
  #pragma unroll
  for(int o=32;o>=1;o>>=1){
    sm0+=__shfl_xor(sm0,o); sm1+=__shfl_xor(sm1,o); sm2+=__shfl_xor(sm2,o); sm3+=__shfl_xor(sm3,o);
  }
  float i0=1.f/(sm0+1e-16f), i1=1.f/(sm1+1e-16f), i2=1.f/(sm2+1e-16f), i3=1.f/(sm3+1e-16f);
  float* so = sOut + (size_t)n*(HH*CC);
  so[0*CC+lane]=acc0*i0; so[0*CC+lane+64]=acc1*i0;
  so[1*CC+lane]=acc2*i1; so[1*CC+lane+64]=acc3*i1;
  so[2*CC+lane]=acc4*i2; so[2*CC+lane+64]=acc5*i2;
  so[3*CC+lane]=acc6*i3; so[3*CC+lane+64]=acc7*i3;
}

// ---------------- GEMM [N,512]@[512,128] + bias + LN + residual ----------------
__global__ __launch_bounds__(256) void k_gemm_ln(
    const float* __restrict__ sIn, const float* __restrict__ W,
    const float* __restrict__ bias, const float* __restrict__ lng, const float* __restrict__ lnb,
    float* __restrict__ xh, int N)
{
  __shared__ float sA[GR*KC];
  __shared__ float sB[KC*CC];
  int t = threadIdx.x;
  int row0 = blockIdx.x*GR;
  int rg = t >> 5;
  int cg = t & 31;
  float acc[4][4];
  #pragma unroll
  for(int i=0;i<4;i++){ acc[i][0]=0.f; acc[i][1]=0.f; acc[i][2]=0.f; acc[i][3]=0.f; }
  for(int k0=0;k0<HH*CC;k0+=KC){
    for(int i=t;i<GR*KC/4;i+=256){
      int r = i/(KC/4); int kq = i%(KC/4);
      int gr = row0+r;
      float4 v = make_float4(0.f,0.f,0.f,0.f);
      if(gr<N) v = *(const float4*)&sIn[(size_t)gr*(HH*CC) + k0 + kq*4];
      *(float4*)&sA[r*KC + kq*4] = v;
    }
    for(int i=t;i<KC*CC/4;i+=256){
      int kk = i/(CC/4); int cq = i%(CC/4);
      *(float4*)&sB[kk*CC + cq*4] = *(const float4*)&W[(size_t)(k0+kk)*CC + cq*4];
    }
    __syncthreads();
    #pragma unroll 4
    for(int k=0;k<KC;k++){
      float a0=sA[(rg*4+0)*KC+k], a1=sA[(rg*4+1)*KC+k], a2=sA[(rg*4+2)*KC+k], a3=sA[(rg*4+3)*KC+k];
      float4 bv = *(const float4*)&sB[k*CC + cg*4];
      acc[0][0]+=a0*bv.x; acc[0][1]+=a0*bv.y; acc[0][2]+=a0*bv.z; acc[0][3]+=a0*bv.w;
      acc[1][0]+=a1*bv.x; acc[1][1]+=a1*bv.y; acc[1][2]+=a1*bv.z; acc[1][3]+=a1*bv.w;
      acc[2][0]+=a2*bv.x; acc[2][1]+=a2*bv.y; acc[2][2]+=a2*bv.z; acc[2][3]+=a2*bv.w;
      acc[3][0]+=a3*bv.x; acc[3][1]+=a3*bv.y; acc[3][2]+=a3*bv.z; acc[3][3]+=a3*bv.w;
    }
    __syncthreads();
  }
  float* out = sB;
  #pragma unroll
  for(int i=0;i<4;i++)
    #pragma unroll
    for(int j=0;j<4;j++)
      out[(rg*4+i)*CC + cg*4+j] = acc[i][j] + bias[cg*4+j];
  __syncthreads();
  int row = t>>3, sub = t&7;
  int gr = row0+row;
  float sum=0.f;
  for(int c=sub*16;c<sub*16+16;c++) sum += out[row*CC+c];
  #pragma unroll
  for(int o=1;o<8;o<<=1) sum += __shfl_xor(sum,o);
  float mu = sum*(1.f/CC);
  float vs=0.f;
  for(int c=sub*16;c<sub*16+16;c++){ float d=out[row*CC+c]-mu; vs+=d*d; }
  #pragma unroll
  for(int o=1;o<8;o<<=1) vs += __shfl_xor(vs,o);
  float inv = rsqrtf(vs*(1.f/CC)+LNEPS);
  if(gr<N){
    for(int c=sub*16;c<sub*16+16;c++){
      size_t gi = (size_t)gr*CC+c;
      xh[gi] = (out[row*CC+c]-mu)*inv*lng[c] + lnb[c] + xh[gi];
    }
  }
}

// ---------------- Set2Set ----------------
__global__ __launch_bounds__(512) void k_lstm(const float* __restrict__ wih, const float* __restrict__ whh,
                    const float* __restrict__ bih, const float* __restrict__ bhh,
                    const float* __restrict__ qstar, float* __restrict__ hS, float* __restrict__ cS){
  __shared__ float sq[2*CC];
  __shared__ float sh[CC];
  __shared__ float sg[4*CC];
  int t=threadIdx.x;
  if(t<2*CC) sq[t]=qstar[t];
  else if(t<3*CC) sh[t-2*CC]=hS[t-2*CC];
  __syncthreads();
  float a=bih[t]+bhh[t];
  const float* wr = wih + (size_t)t*2*CC;
  for(int j=0;j<2*CC;j++) a += wr[j]*sq[j];
  const float* hr = whh + (size_t)t*CC;
  for(int j=0;j<CC;j++) a += hr[j]*sh[j];
  sg[t]=a;
  __syncthreads();
  if(t<CC){
    float gi=sg[t], gf=sg[CC+t], gg=sg[2*CC+t], go=sg[3*CC+t];
    float c = 1.f/(1.f+expf(-gf))*cS[t] + 1.f/(1.f+expf(-gi))*tanhf(gg);
    float h = 1.f/(1.f+expf(-go))*tanhf(c);
    cS[t]=c; hS[t]=h;
  }
}

__global__ __launch_bounds__(256) void k_scores(const float* __restrict__ xh, const float* __restrict__ q,
                                                float* __restrict__ sc, u32* __restrict__ scmax, int N){
  int t=threadIdx.x; int wave=t>>6, lane=t&63;
  float q0=q[lane], q1=q[lane+64];
  float wmax=-1e30f;
  for(int n=blockIdx.x*4+wave; n<N; n+=gridDim.x*4){
    const float* xr = xh+(size_t)n*CC;
    float v = xr[lane]*q0 + xr[lane+64]*q1;
    #pragma unroll
    for(int o=32;o>=1;o>>=1) v += __shfl_xor(v,o);
    if(lane==0) sc[n]=v;
    wmax = fmaxf(wmax,v);
  }
  __shared__ float sm[4];
  if(lane==0) sm[wave]=wmax;
  __syncthreads();
  if(t==0){
    float m = fmaxf(fmaxf(sm[0],sm[1]),fmaxf(sm[2],sm[3]));
    atomicMax(scmax, fenc(m));
  }
}

__global__ __launch_bounds__(256) void k_r(const float* __restrict__ xh, const float* __restrict__ sc,
                                           const u32* __restrict__ scmax, float* __restrict__ r,
                                           float* __restrict__ total, int N){
  int t=threadIdx.x; int c = t&(CC-1); int half = t>>7;
  float mx = fdec(*scmax);
  float acc=0.f, et=0.f;
  for(int n=blockIdx.x*2+half; n<N; n+=gridDim.x*2){
    float e = expf(sc[n]-mx);
    acc += e*xh[(size_t)n*CC+c];
    et += (c==0)? e : 0.f;
  }
  __shared__ float sacc[256];
  __shared__ float set_[2];
  sacc[t]=acc;
  if(c==0) set_[half]=et;
  __syncthreads();
  if(t<CC) atomicAdd(&r[t], sacc[t]+sacc[t+CC]);
  if(t==0) atomicAdd(total, set_[0]+set_[1]);
}

__global__ void k_finalize(const float* __restrict__ hS, const float* __restrict__ r,
                           const float* __restrict__ total, float* __restrict__ qstar){
  int t=threadIdx.x;
  if(t<CC) qstar[t]=hS[t];
  else if(t<2*CC) qstar[t]=r[t-CC]/total[0];
}

// ---------------- output MLP ----------------
__global__ __launch_bounds__(256) void k_out(
  const float* __restrict__ qstar, const float* __restrict__ vvec,
  const float* __restrict__ w1, const float* __restrict__ b1,
  const float* __restrict__ w2, const float* __restrict__ b2,
  const float* __restrict__ w3, const float* __restrict__ b3, float* __restrict__ out)
{
  __shared__ float comb[3*CC];
  __shared__ float o1[CC];
  __shared__ float o2[64];
  int t=threadIdx.x;
  if(t<2*CC) comb[t]=qstar[t];
  if(t<CC) comb[2*CC+t]=vvec[t];
  __syncthreads();
  if(t<CC){
    float a=b1[t];
    for(int j=0;j<3*CC;j++) a += comb[j]*w1[j*CC+t];
    o1[t]=fmaxf(a,0.f);
  }
  __syncthreads();
  if(t<64){
    float a=b2[t];
    for(int j=0;j<CC;j++) a += o1[j]*w2[j*64+t];
    o2[t]=fmaxf(a,0.f);
  }
  __syncthreads();
  {
    float a=b3[t];
    for(int j=0;j<64;j++) a += o2[j]*w3[j*256+t];
    out[t]=fmaxf(a,0.f);
  }
}

extern "C" void kernel_launch(void* const* d_in, const int* in_sizes, int n_in,
                              void* d_out, int out_size, void* d_ws, size_t ws_size,
                              hipStream_t stream){
  (void)n_in; (void)out_size; (void)ws_size;
  const float* x        = (const float*)d_in[0];
  const int*   eidx     = (const int*)  d_in[1];
  const float* edge_attr= (const float*)d_in[2];
  const float* vnf      = (const float*)d_in[3];
  const float* w_node   = (const float*)d_in[4];
  const float* b_node   = (const float*)d_in[5];
  const float* w_ee     = (const float*)d_in[6];
  const float* b_ee     = (const float*)d_in[7];
  const float* w_ep     = (const float*)d_in[8];
  const float* b_ep     = (const float*)d_in[9];
  const float* w_vnf    = (const float*)d_in[10];
  const float* b_vnf    = (const float*)d_in[11];
  const float* attn_w1  = (const float*)d_in[12];
  const float* attn_b1  = (const float*)d_in[13];
  const float* attn_w2  = (const float*)d_in[14];
  const float* attn_b2  = (const float*)d_in[15];
  const float* attn_w3  = (const float*)d_in[16];
  const float* attn_b3  = (const float*)d_in[17];
  const float* gat_w    = (const float*)d_in[18];
  const float* att_src  = (const float*)d_in[19];
  const float* att_dst  = (const float*)d_in[20];
  const float* gat_we   = (const float*)d_in[21];
  const float* att_e    = (const float*)d_in[22];
  const float* gat_b    = (const float*)d_in[23];
  const float* ln_g     = (const float*)d_in[24];
  const float* ln_b     = (const float*)d_in[25];
  const float* venc_w1  = (const float*)d_in[26];
  const float* venc_b1  = (const float*)d_in[27];
  const float* venc_w2  = (const float*)d_in[28];
  const float* venc_b2  = (const float*)d_in[29];
  const float* lstm_wih = (const float*)d_in[30];
  const float* lstm_whh = (const float*)d_in[31];
  const float* lstm_bih = (const float*)d_in[32];
  const float* lstm_bhh = (const float*)d_in[33];
  const float* out_w1   = (const float*)d_in[34];
  const float* out_b1   = (const float*)d_in[35];
  const float* out_w2   = (const float*)d_in[36];
  const float* out_b2   = (const float*)d_in[37];
  const float* out_w3   = (const float*)d_in[38];
  const float* out_b3   = (const float*)d_in[39];

  const int N = in_sizes[0]/8;
  const int E = in_sizes[1]/2;
  const int* srcA = eidx;
  const int* dstA = eidx + E;

  char* wp = (char*)d_ws;
  auto alloc = [&](size_t bytes)->void*{ void* p=(void*)wp; wp += (bytes+255)&~(size_t)255; return p; };
  float* xh    = (float*)alloc((size_t)N*CC*4);           // 25.6 MB
  float* sbuf  = (float*)alloc((size_t)N*CC*HH*4);        // 102.4 MB
  float* a_e   = (float*)alloc((size_t)LL*E*HH*4);        // 9.6 MB
  float* asrc  = (float*)alloc((size_t)N*HH*4);
  float* adst  = (float*)alloc((size_t)N*HH*4);
  int* counts  = (int*)alloc((size_t)N*4);
  int* offsets = (int*)alloc((size_t)(N+1)*4);
  int* cursor  = (int*)alloc((size_t)N*4);
  int* elist   = (int*)alloc((size_t)E*4);
  float* sc    = (float*)alloc((size_t)N*4);
  float* wattS = (float*)alloc((size_t)LL*CC*HH*4);
  float* wattD = (float*)alloc((size_t)LL*CC*HH*4);
  float* wattE = (float*)alloc((size_t)LL*CC*HH*4);
  float* We    = (float*)alloc(4*CC*4);
  float* be    = (float*)alloc(CC*4);
  float* vemb  = (float*)alloc(CC*4);
  float* Wh1   = (float*)alloc(4*CC*4);
  float* bh1   = (float*)alloc(CC*4);
  float* aelin = (float*)alloc(48*4);
  float* aebias= (float*)alloc(12*4);
  float* Wbig  = (float*)alloc((size_t)LL*HH*CC*CC*4);    // 786 KB
  float* vvec  = (float*)alloc(CC*4);
  float* lbuf  = (float*)alloc(4*CC*4);
  float* hS=lbuf; float* cS=lbuf+CC; float* qstar=lbuf+2*CC;
  float* s2s   = (float*)alloc(130*4);                    // [0]=scmax(u32) [1]=total [2..129]=r

  k_att_collapse<<<6,256,0,stream>>>(gat_w, att_src, wattS);
  k_att_collapse<<<6,256,0,stream>>>(gat_w, att_dst, wattD);
  k_att_collapse<<<6,256,0,stream>>>(gat_we, att_e, wattE);
  k_We<<<2,256,0,stream>>>(w_ee, w_ep, We);
  k_be_vemb<<<1,256,0,stream>>>(b_ee, w_ep, b_ep, vnf, w_vnf, b_vnf, be, vemb);
  k_h1eff<<<3,256,0,stream>>>(We, be, vemb, attn_w1, attn_b1, Wh1, bh1);
  k_aelin<<<1,64,0,stream>>>(We, be, wattE, aelin, aebias);
  k_wbig<<<(LL*HH*CC*CC+255)/256,256,0,stream>>>(gat_w, Wbig);
  k_vvec<<<1,CC,0,stream>>>(vnf, venc_w1, venc_b1, venc_w2, venc_b2, vvec);
  k_node_embed<<<(N*CC+255)/256,256,0,stream>>>(x, w_node, b_node, xh, N);

  hipMemsetAsync(counts, 0, (size_t)N*4, stream);
  k_count<<<(E+255)/256,256,0,stream>>>(dstA, counts, E);
  k_scan<<<1,1024,0,stream>>>(counts, offsets, N);
  hipMemsetAsync(cursor, 0, (size_t)N*4, stream);
  k_fill<<<(E+255)/256,256,0,stream>>>(dstA, offsets, cursor, elist, E);

  k_edge_attn<<<2048,256,0,stream>>>(edge_attr, Wh1, bh1, attn_w2, attn_b2, attn_w3, attn_b3, aelin, aebias, a_e, E);

  for(int l=0;l<LL;l++){
    k_node_ad<<<(N*8+255)/256,256,0,stream>>>(xh, wattS+(size_t)l*CC*HH, wattD+(size_t)l*CC*HH, asrc, adst, N);
    k_aggregate<<<(N+3)/4,256,0,stream>>>(xh, srcA, a_e+(size_t)l*E*HH, asrc, adst, offsets, elist, sbuf, N);
    k_gemm_ln<<<(N+GR-1)/GR,256,0,stream>>>(sbuf, Wbig+(size_t)l*HH*CC*CC, gat_b+(size_t)l*CC,
                                            ln_g+(size_t)l*CC, ln_b+(size_t)l*CC, xh, N);
  }

  hipMemsetAsync(lbuf, 0, 4*CC*4, stream);
  for(int it=0; it<3; ++it){
    k_lstm<<<1,512,0,stream>>>(lstm_wih, lstm_whh, lstm_bih, lstm_bhh, qstar, hS, cS);
    hipMemsetAsync(s2s, 0, 130*4, stream);
    k_scores<<<512,256,0,stream>>>(xh, hS, sc, (u32*)s2s, N);
    k_r<<<512,256,0,stream>>>(xh, sc, (u32*)s2s, s2s+2, s2s+1, N);
    k_finalize<<<1,256,0,stream>>>(hS, s2s+2, s2s+1, qstar);
  }

  k_out<<<1,256,0,stream>>>(qstar, vvec, out_w1, out_b1, out_w2, out_b2, out_w3, out_b3, (float*)d_out);
}

// Round 3
// 1061.548 us; speedup vs baseline: 1.0973x; 1.0973x over previous
//
#include <hip/hip_runtime.h>
#include <math.h>

#define CC 128
#define HH 4
#define LL 3
#define LNEPS 1e-5f
#define GR 32
#define KC 64

typedef unsigned int u32;

__device__ __forceinline__ u32 fenc(float f){ u32 u=__float_as_uint(f); return (u&0x80000000u)? ~u : (u|0x80000000u); }
__device__ __forceinline__ float fdec(u32 u){ return (u&0x80000000u)? __uint_as_float(u&0x7FFFFFFFu) : __uint_as_float(~u); }

// ---------------- tiny precompute kernels ----------------

__global__ void k_att_collapse(const float* __restrict__ W, const float* __restrict__ att, float* __restrict__ out){
  int idx = blockIdx.x*blockDim.x + threadIdx.x;
  if(idx >= LL*CC*HH) return;
  int h = idx % HH; int k = (idx/HH)%CC; int l = idx/(HH*CC);
  const float* w = W + ((size_t)(l*CC+k))*(HH*CC) + h*CC;
  const float* a = att + (size_t)(l*HH+h)*CC;
  float s=0.f;
  for(int c=0;c<CC;c++) s += w[c]*a[c];
  out[idx] = s;
}

__global__ void k_We(const float* __restrict__ w_ee, const float* __restrict__ w_ep, float* __restrict__ We){
  int idx = blockIdx.x*blockDim.x + threadIdx.x;
  if(idx >= 4*CC) return;
  int c = idx & (CC-1); int k = idx >> 7;
  float s=0.f;
  for(int m=0;m<CC;m++) s += w_ee[k*CC+m]*w_ep[m*CC+c];
  We[idx]=s;
}

__global__ void k_be_vemb(const float* __restrict__ b_ee, const float* __restrict__ w_ep, const float* __restrict__ b_ep,
                          const float* __restrict__ vnf, const float* __restrict__ w_vnf, const float* __restrict__ b_vnf,
                          float* __restrict__ be, float* __restrict__ vemb){
  int t = threadIdx.x;
  if(t<CC){
    float s=b_ep[t];
    for(int m=0;m<CC;m++) s += b_ee[m]*w_ep[m*CC+t];
    be[t]=s;
  } else if(t<2*CC){
    int c=t-CC;
    float s=b_vnf[c];
    for(int j=0;j<6;j++) s += vnf[j]*w_vnf[j*CC+c];
    vemb[c]=s;
  }
}

__global__ void k_h1eff(const float* __restrict__ We, const float* __restrict__ be, const float* __restrict__ vemb,
                        const float* __restrict__ w1, const float* __restrict__ b1,
                        float* __restrict__ Wh1, float* __restrict__ bh1){
  int idx = blockIdx.x*blockDim.x + threadIdx.x;
  if(idx < 4*CC){
    int c = idx & (CC-1); int k = idx>>7;
    float s=0.f;
    for(int m=0;m<CC;m++) s += We[k*CC+m]*w1[m*CC+c];
    Wh1[idx]=s;
  } else if(idx < 5*CC){
    int c = idx - 4*CC;
    float s=b1[c];
    for(int m=0;m<CC;m++) s += be[m]*w1[m*CC+c];
    for(int j=0;j<CC;j++) s += vemb[j]*w1[(CC+j)*CC+c];
    bh1[c]=s;
  }
}

__global__ void k_aelin(const float* __restrict__ We, const float* __restrict__ be, const float* __restrict__ wattE,
                        float* __restrict__ aelin, float* __restrict__ aebias){
  int t = threadIdx.x;
  if(t<48){
    int l=t>>4, k=(t>>2)&3, h=t&3;
    float s=0.f;
    for(int m=0;m<CC;m++) s += We[k*CC+m]*wattE[(size_t)(l*CC+m)*HH+h];
    aelin[t]=s;
  } else if(t<60){
    int i=t-48; int l=i>>2, h=i&3;
    float s=0.f;
    for(int m=0;m<CC;m++) s += be[m]*wattE[(size_t)(l*CC+m)*HH+h];
    aebias[i]=s;
  }
}

__global__ void k_wbig(const float* __restrict__ gat_w, float* __restrict__ Wbig){
  int idx = blockIdx.x*blockDim.x + threadIdx.x;
  if(idx >= LL*HH*CC*CC) return;
  int c = idx & (CC-1);
  int hk = (idx>>7) & 511;
  int l = idx >> 16;
  int h = hk >> 7; int k = hk & 127;
  Wbig[idx] = gat_w[((size_t)(l*CC+k))*(HH*CC) + h*CC + c] * 0.25f;
}

__global__ void k_vvec(const float* __restrict__ vnf, const float* __restrict__ w1, const float* __restrict__ b1,
                       const float* __restrict__ w2, const float* __restrict__ b2, float* __restrict__ v){
  __shared__ float hv[CC];
  int t=threadIdx.x;
  float s=b1[t];
  for(int j=0;j<6;j++) s += vnf[j]*w1[j*CC+t];
  hv[t]=fmaxf(s,0.f);
  __syncthreads();
  float o=b2[t];
  for(int j=0;j<CC;j++) o += hv[j]*w2[j*CC+t];
  v[t]=o;
}

// ---------------- node embedding ----------------
__global__ void k_node_embed(const float* __restrict__ x, const float* __restrict__ w, const float* __restrict__ b,
                             float* __restrict__ xh, int N){
  int idx=blockIdx.x*blockDim.x+threadIdx.x;
  if(idx>=N*CC) return;
  int c=idx&(CC-1); int n=idx>>7;
  const float* xr = x+(size_t)n*8;
  float s=b[c];
  #pragma unroll
  for(int k=0;k<8;k++) s += xr[k]*w[k*CC+c];
  xh[idx]=s;
}

// ---------------- CSR by dst ----------------
__global__ void k_count(const int* __restrict__ dst, int* __restrict__ counts, int E){
  int e=blockIdx.x*blockDim.x+threadIdx.x;
  if(e<E) atomicAdd(&counts[dst[e]],1);
}

__global__ __launch_bounds__(1024) void k_scan(const int* __restrict__ counts, int* __restrict__ offsets, int N){
  __shared__ int sv[1024];
  int t=threadIdx.x;
  int per=(N+1023)/1024;
  int b=t*per; int e=b+per; if(e>N)e=N; if(b>N)b=N;
  int ssum=0;
  for(int i=b;i<e;i++) ssum+=counts[i];
  sv[t]=ssum;
  __syncthreads();
  for(int off=1;off<1024;off<<=1){
    int add = (t>=off)? sv[t-off]:0;
    __syncthreads();
    sv[t]+=add;
    __syncthreads();
  }
  int run = sv[t]-ssum;
  for(int i=b;i<e;i++){ offsets[i]=run; run+=counts[i]; }
  if(t==1023) offsets[N]=sv[1023];
}

__global__ void k_fill(const int* __restrict__ dst, const int* __restrict__ offsets, int* __restrict__ cursor,
                       int* __restrict__ elist, int E){
  int e=blockIdx.x*blockDim.x+threadIdx.x;
  if(e<E){ int d=dst[e]; int pos=atomicAdd(&cursor[d],1); elist[offsets[d]+pos]=e; }
}

// ---------------- fused edge-attention MLP -> a_e[l][e][h] (64-edge tile GEMM) ----------------
__global__ __launch_bounds__(256) void k_edge_attn(
    const float* __restrict__ edge_attr,
    const float* __restrict__ Wh1, const float* __restrict__ bh1,
    const float* __restrict__ attn_w2, const float* __restrict__ attn_b2,
    const float* __restrict__ attn_w3, const float* __restrict__ attn_b3,
    const float* __restrict__ aelin, const float* __restrict__ aebias,
    float* __restrict__ a_e, int E)
{
  __shared__ float s_w2[CC*64];      // [c][o] 32KB
  __shared__ float s_h1t[64*64];     // [k_half][edge] 16KB
  __shared__ float s_eat[4*64];      // [k][edge] 1KB
  __shared__ float s_wh1t[CC*4];     // [c][k] 2KB
  __shared__ float s_bh1[CC];
  __shared__ float s_b2[64];
  __shared__ float s_w3[64];
  __shared__ float s_lin[48];
  __shared__ float s_lbias[12];
  int t = threadIdx.x;
  for(int i=t;i<CC*64;i+=256) s_w2[i]=attn_w2[i];
  for(int i=t;i<CC*4;i+=256){ int c=i>>2, k=i&3; s_wh1t[i]=Wh1[k*CC+c]; }
  if(t<CC) s_bh1[t]=bh1[t];
  else if(t<CC+64) s_b2[t-CC]=attn_b2[t-CC];
  else if(t<CC+128) s_w3[t-CC-64]=attn_w3[t-CC-64];
  if(t<48) s_lin[t]=aelin[t];            // FIX: separate chain, fits in 256 threads
  else if(t<60) s_lbias[t-48]=aebias[t-48];
  float b3v = attn_b3[0];
  int e0 = blockIdx.x*64;
  if(t<64){
    int e=e0+t;
    float4 v = (e<E)? *(const float4*)&edge_attr[(size_t)e*4] : make_float4(0.f,0.f,0.f,0.f);
    s_eat[t]=v.x; s_eat[64+t]=v.y; s_eat[128+t]=v.z; s_eat[192+t]=v.w;
  }
  int eg=t>>4, og=t&15;
  float acc[4][4];
  #pragma unroll
  for(int i=0;i<4;i++){ acc[i][0]=0.f; acc[i][1]=0.f; acc[i][2]=0.f; acc[i][3]=0.f; }
  for(int half=0;half<2;half++){
    __syncthreads();
    for(int i=t;i<64*64;i+=256){
      int kl=i>>6, e=i&63, k=half*64+kl;
      float4 w = *(const float4*)&s_wh1t[k*4];
      float v = s_bh1[k] + s_eat[e]*w.x + s_eat[64+e]*w.y + s_eat[128+e]*w.z + s_eat[192+e]*w.w;
      s_h1t[i] = fmaxf(v,0.f);
    }
    __syncthreads();
    const float* w2h = s_w2 + half*4096;
    #pragma unroll 8
    for(int k=0;k<64;k++){
      float4 a = *(const float4*)&s_h1t[k*64 + eg*4];
      float4 b = *(const float4*)&w2h[k*64 + og*4];
      acc[0][0]+=a.x*b.x; acc[0][1]+=a.x*b.y; acc[0][2]+=a.x*b.z; acc[0][3]+=a.x*b.w;
      acc[1][0]+=a.y*b.x; acc[1][1]+=a.y*b.y; acc[1][2]+=a.y*b.z; acc[1][3]+=a.y*b.w;
      acc[2][0]+=a.z*b.x; acc[2][1]+=a.z*b.y; acc[2][2]+=a.z*b.z; acc[2][3]+=a.z*b.w;
      acc[3][0]+=a.w*b.x; acc[3][1]+=a.w*b.y; acc[3][2]+=a.w*b.z; acc[3][3]+=a.w*b.w;
    }
  }
  float4 b2v = *(const float4*)&s_b2[og*4];
  float4 w3v = *(const float4*)&s_w3[og*4];
  float att[4];
  #pragma unroll
  for(int i=0;i<4;i++){
    float p = fmaxf(acc[i][0]+b2v.x,0.f)*w3v.x + fmaxf(acc[i][1]+b2v.y,0.f)*w3v.y
            + fmaxf(acc[i][2]+b2v.z,0.f)*w3v.z + fmaxf(acc[i][3]+b2v.w,0.f)*w3v.w;
    #pragma unroll
    for(int off=1;off<16;off<<=1) p += __shfl_xor(p,off);
    att[i] = 1.f/(1.f+expf(-(p+b3v)));
  }
  if(og<12){
    int l=og>>2, h=og&3;
    float w0=s_lin[l*16+h], w1=s_lin[l*16+4+h], w2x=s_lin[l*16+8+h], w3x=s_lin[l*16+12+h];
    float lb=s_lbias[l*4+h];
    #pragma unroll
    for(int i=0;i<4;i++){
      int el=eg*4+i; int e=e0+el;
      if(e<E){
        float v = s_eat[el]*w0 + s_eat[64+el]*w1 + s_eat[128+el]*w2x + s_eat[192+el]*w3x + lb;
        a_e[((size_t)l*E+e)*4+h] = att[i]*v;
      }
    }
  }
}

// ---------------- per-node attention logits ----------------
__global__ void k_node_ad(const float* __restrict__ xh, const float* __restrict__ wS, const float* __restrict__ wD,
                          float* __restrict__ asrc, float* __restrict__ adst, int N){
  int idx = blockIdx.x*blockDim.x + threadIdx.x;
  if(idx >= N*8) return;
  int o = idx & 7; int n = idx >> 3;
  const float* w = ((o<4)? wS : wD) + (o&3);
  const float* xr = xh + (size_t)n*CC;
  float s=0.f;
  for(int k=0;k<CC;k++) s += xr[k]*w[(size_t)k*HH];
  ((o<4)? asrc : adst)[n*4+(o&3)] = s;
}

// ---------------- per-dst GAT aggregation (wave per node, no atomics) ----------------
__global__ __launch_bounds__(256) void k_aggregate(
    const float* __restrict__ xh, const int* __restrict__ srcArr,
    const float* __restrict__ aeL, const float* __restrict__ asrc, const float* __restrict__ adst,
    const int* __restrict__ offsets, const int* __restrict__ elist,
    float* __restrict__ sOut, int N)
{
  int wave = threadIdx.x>>6, lane = threadIdx.x&63;
  int n = blockIdx.x*4+wave;
  if(n>=N) return;
  int beg = offsets[n];
  int deg = offsets[n+1]-beg;
  const float4* ae4 = (const float4*)aeL;
  const float4* as4 = (const float4*)asrc;
  float4 ad = ((const float4*)adst)[n];
  float mx0=-1e30f,mx1=-1e30f,mx2=-1e30f,mx3=-1e30f;
  for(int base=0;base<deg;base+=64){
    int i=base+lane;
    if(i<deg){
      int e = elist[beg+i];
      float4 ae = ae4[e];
      float4 as = as4[srcArr[e]];
      float a0=as.x+ad.x+ae.x; a0=(a0>0.f)?a0:0.2f*a0;
      float a1=as.y+ad.y+ae.y; a1=(a1>0.f)?a1:0.2f*a1;
      float a2=as.z+ad.z+ae.z; a2=(a2>0.f)?a2:0.2f*a2;
      float a3=as.w+ad.w+ae.w; a3=(a3>0.f)?a3:0.2f*a3;
      mx0=fmaxf(mx0,a0); mx1=fmaxf(mx1,a1); mx2=fmaxf(mx2,a2); mx3=fmaxf(mx3,a3);
    }
  }
  #pragma unroll
  for(int o=32;o>=1;o>>=1){
    mx0=fmaxf(mx0,__shfl_xor(mx0,o));
    mx1=fmaxf(mx1,__shfl_xor(mx1,o));
    mx2=fmaxf(mx2,__shfl_xor(mx2,o));
    mx3=fmaxf(mx3,__shfl_xor(mx3,o));
  }
  float sm0=0,sm1=0,sm2=0,sm3=0;
  float acc0=0,acc1=0,acc2=0,acc3=0,acc4=0,acc5=0,acc6=0,acc7=0;
  for(int base=0;base<deg;base+=64){
    int i=base+lane;
    float ex0=0,ex1=0,ex2=0,ex3=0; int mysrc=0;
    if(i<deg){
      int e = elist[beg+i];
      mysrc = srcArr[e];
      float4 ae = ae4[e];
      float4 as = as4[mysrc];
      float a0=as.x+ad.x+ae.x; a0=(a0>0.f)?a0:0.2f*a0;
      float a1=as.y+ad.y+ae.y; a1=(a1>0.f)?a1:0.2f*a1;
      float a2=as.z+ad.z+ae.z; a2=(a2>0.f)?a2:0.2f*a2;
      float a3=as.w+ad.w+ae.w; a3=(a3>0.f)?a3:0.2f*a3;
      ex0=expf(a0-mx0); ex1=expf(a1-mx1); ex2=expf(a2-mx2); ex3=expf(a3-mx3);
      sm0+=ex0; sm1+=ex1; sm2+=ex2; sm3+=ex3;
    }
    int cnt = deg-base; if(cnt>64) cnt=64;
    for(int j=0;j<cnt;j++){
      int sr = __shfl(mysrc,j);
      float al0=__shfl(ex0,j), al1=__shfl(ex1,j), al2=__shfl(ex2,j), al3=__shfl(ex3,j);
      const float* xr = xh + (size_t)sr*CC;
      float x0 = xr[lane], x1 = xr[lane+64];
      acc0 += al0*x0; acc1 += al0*x1;
      acc2 += al1*x0; acc3 += al1*x1;
      acc4 += al2*x0; acc5 += al2*x1;
      acc6 += al3*x0; acc7 += al3*x1;
    }
  }
  #pragma unroll
  for(int o=32;o>=1;o>>=1){
    sm0+=__shfl_xor(sm0,o); sm1+=__shfl_xor(sm1,o); sm2+=__shfl_xor(sm2,o); sm3+=__shfl_xor(sm3,o);
  }
  float i0=1.f/(sm0+1e-16f), i1=1.f/(sm1+1e-16f), i2=1.f/(sm2+1e-16f), i3=1.f/(sm3+1e-16f);
  float* so = sOut + (size_t)n*(HH*CC);
  so[0*CC+lane]=acc0*i0; so[0*CC+lane+64]=acc1*i0;
  so[1*CC+lane]=acc2*i1; so[1*CC+lane+64]=acc3*i1;
  so[2*CC+lane]=acc4*i2; so[2*CC+lane+64]=acc5*i2;
  so[3*CC+lane]=acc6*i3; so[3*CC+lane+64]=acc7*i3;
}

// ---------------- GEMM [N,512]@[512,128] + bias + LN + residual (register LN) ----------------
__global__ __launch_bounds__(256) void k_gemm_ln(
    const float* __restrict__ sIn, const float* __restrict__ W,
    const float* __restrict__ bias, const float* __restrict__ lng, const float* __restrict__ lnb,
    float* __restrict__ xh, int N)
{
  __shared__ float sA[GR*KC];
  __shared__ float sB[KC*CC];
  int t = threadIdx.x;
  int row0 = blockIdx.x*GR;
  int rg = t >> 5;
  int cg = t & 31;
  float acc[4][4];
  #pragma unroll
  for(int i=0;i<4;i++){ acc[i][0]=0.f; acc[i][1]=0.f; acc[i][2]=0.f; acc[i][3]=0.f; }
  for(int k0=0;k0<HH*CC;k0+=KC){
    for(int i=t;i<GR*KC/4;i+=256){
      int r = i/(KC/4); int kq = i%(KC/4);
      int gr = row0+r;
      float4 v = make_float4(0.f,0.f,0.f,0.f);
      if(gr<N) v = *(const float4*)&sIn[(size_t)gr*(HH*CC) + k0 + kq*4];
      *(float4*)&sA[r*KC + kq*4] = v;
    }
    for(int i=t;i<KC*CC/4;i+=256){
      int kk = i/(CC/4); int cq = i%(CC/4);
      *(float4*)&sB[kk*CC + cq*4] = *(const float4*)&W[(size_t)(k0+kk)*CC + cq*4];
    }
    __syncthreads();
    #pragma unroll
    for(int kq=0;kq<KC;kq+=4){
      float4 A0 = *(const float4*)&sA[(rg*4+0)*KC+kq];
      float4 A1 = *(const float4*)&sA[(rg*4+1)*KC+kq];
      float4 A2 = *(const float4*)&sA[(rg*4+2)*KC+kq];
      float4 A3 = *(const float4*)&sA[(rg*4+3)*KC+kq];
      float4 B0 = *(const float4*)&sB[(kq+0)*CC + cg*4];
      float4 B1 = *(const float4*)&sB[(kq+1)*CC + cg*4];
      float4 B2 = *(const float4*)&sB[(kq+2)*CC + cg*4];
      float4 B3 = *(const float4*)&sB[(kq+3)*CC + cg*4];
      acc[0][0]+=A0.x*B0.x; acc[0][1]+=A0.x*B0.y; acc[0][2]+=A0.x*B0.z; acc[0][3]+=A0.x*B0.w;
      acc[1][0]+=A1.x*B0.x; acc[1][1]+=A1.x*B0.y; acc[1][2]+=A1.x*B0.z; acc[1][3]+=A1.x*B0.w;
      acc[2][0]+=A2.x*B0.x; acc[2][1]+=A2.x*B0.y; acc[2][2]+=A2.x*B0.z; acc[2][3]+=A2.x*B0.w;
      acc[3][0]+=A3.x*B0.x; acc[3][1]+=A3.x*B0.y; acc[3][2]+=A3.x*B0.z; acc[3][3]+=A3.x*B0.w;
      acc[0][0]+=A0.y*B1.x; acc[0][1]+=A0.y*B1.y; acc[0][2]+=A0.y*B1.z; acc[0][3]+=A0.y*B1.w;
      acc[1][0]+=A1.y*B1.x; acc[1][1]+=A1.y*B1.y; acc[1][2]+=A1.y*B1.z; acc[1][3]+=A1.y*B1.w;
      acc[2][0]+=A2.y*B1.x; acc[2][1]+=A2.y*B1.y; acc[2][2]+=A2.y*B1.z; acc[2][3]+=A2.y*B1.w;
      acc[3][0]+=A3.y*B1.x; acc[3][1]+=A3.y*B1.y; acc[3][2]+=A3.y*B1.z; acc[3][3]+=A3.y*B1.w;
      acc[0][0]+=A0.z*B2.x; acc[0][1]+=A0.z*B2.y; acc[0][2]+=A0.z*B2.z; acc[0][3]+=A0.z*B2.w;
      acc[1][0]+=A1.z*B2.x; acc[1][1]+=A1.z*B2.y; acc[1][2]+=A1.z*B2.z; acc[1][3]+=A1.z*B2.w;
      acc[2][0]+=A2.z*B2.x; acc[2][1]+=A2.z*B2.y; acc[2][2]+=A2.z*B2.z; acc[2][3]+=A2.z*B2.w;
      acc[3][0]+=A3.z*B2.x; acc[3][1]+=A3.z*B2.y; acc[3][2]+=A3.z*B2.z; acc[3][3]+=A3.z*B2.w;
      acc[0][0]+=A0.w*B3.x; acc[0][1]+=A0.w*B3.y; acc[0][2]+=A0.w*B3.z; acc[0][3]+=A0.w*B3.w;
      acc[1][0]+=A1.w*B3.x; acc[1][1]+=A1.w*B3.y; acc[1][2]+=A1.w*B3.z; acc[1][3]+=A1.w*B3.w;
      acc[2][0]+=A2.w*B3.x; acc[2][1]+=A2.w*B3.y; acc[2][2]+=A2.w*B3.z; acc[2][3]+=A2.w*B3.w;
      acc[3][0]+=A3.w*B3.x; acc[3][1]+=A3.w*B3.y; acc[3][2]+=A3.w*B3.z; acc[3][3]+=A3.w*B3.w;
    }
    __syncthreads();
  }
  // LN + residual in registers, exact two-pass form
  float4 bb = *(const float4*)&bias[cg*4];
  float4 gg = *(const float4*)&lng[cg*4];
  float4 eb = *(const float4*)&lnb[cg*4];
  #pragma unroll
  for(int i=0;i<4;i++){
    float x0=acc[i][0]+bb.x, x1=acc[i][1]+bb.y, x2=acc[i][2]+bb.z, x3=acc[i][3]+bb.w;
    float s = x0+x1+x2+x3;
    #pragma unroll
    for(int off=1;off<32;off<<=1) s += __shfl_xor(s,off);
    float mu = s*(1.f/CC);
    float d0=x0-mu, d1=x1-mu, d2=x2-mu, d3=x3-mu;
    float q = d0*d0+d1*d1+d2*d2+d3*d3;
    #pragma unroll
    for(int off=1;off<32;off<<=1) q += __shfl_xor(q,off);
    float inv = rsqrtf(q*(1.f/CC) + LNEPS);
    int gr = row0 + rg*4 + i;
    if(gr<N){
      size_t gi = (size_t)gr*CC + cg*4;
      float4 old = *(const float4*)&xh[gi];
      float4 o;
      o.x = d0*inv*gg.x + eb.x + old.x;
      o.y = d1*inv*gg.y + eb.y + old.y;
      o.z = d2*inv*gg.z + eb.z + old.z;
      o.w = d3*inv*gg.w + eb.w + old.w;
      *(float4*)&xh[gi] = o;
    }
  }
}

// ---------------- Set2Set ----------------
__global__ __launch_bounds__(512) void k_lstm(const float* __restrict__ wih, const float* __restrict__ whh,
                    const float* __restrict__ bih, const float* __restrict__ bhh,
                    const float* __restrict__ qstar, float* __restrict__ hS, float* __restrict__ cS){
  __shared__ float sq[2*CC];
  __shared__ float sh[CC];
  __shared__ float sg[4*CC];
  int t=threadIdx.x;
  if(t<2*CC) sq[t]=qstar[t];
  else if(t<3*CC) sh[t-2*CC]=hS[t-2*CC];
  __syncthreads();
  float a=bih[t]+bhh[t];
  const float* wr = wih + (size_t)t*2*CC;
  for(int j=0;j<2*CC;j++) a += wr[j]*sq[j];
  const float* hr = whh + (size_t)t*CC;
  for(int j=0;j<CC;j++) a += hr[j]*sh[j];
  sg[t]=a;
  __syncthreads();
  if(t<CC){
    float gi=sg[t], gf=sg[CC+t], gg=sg[2*CC+t], go=sg[3*CC+t];
    float c = 1.f/(1.f+expf(-gf))*cS[t] + 1.f/(1.f+expf(-gi))*tanhf(gg);
    float h = 1.f/(1.f+expf(-go))*tanhf(c);
    cS[t]=c; hS[t]=h;
  }
}

__global__ __launch_bounds__(256) void k_scores(const float* __restrict__ xh, const float* __restrict__ q,
                                                float* __restrict__ sc, u32* __restrict__ scmax, int N){
  int t=threadIdx.x; int wave=t>>6, lane=t&63;
  float q0=q[lane], q1=q[lane+64];
  float wmax=-1e30f;
  for(int n=blockIdx.x*4+wave; n<N; n+=gridDim.x*4){
    const float* xr = xh+(size_t)n*CC;
    float v = xr[lane]*q0 + xr[lane+64]*q1;
    #pragma unroll
    for(int o=32;o>=1;o>>=1) v += __shfl_xor(v,o);
    if(lane==0) sc[n]=v;
    wmax = fmaxf(wmax,v);
  }
  __shared__ float sm[4];
  if(lane==0) sm[wave]=wmax;
  __syncthreads();
  if(t==0){
    float m = fmaxf(fmaxf(sm[0],sm[1]),fmaxf(sm[2],sm[3]));
    atomicMax(scmax, fenc(m));
  }
}

__global__ __launch_bounds__(256) void k_r(const float* __restrict__ xh, const float* __restrict__ sc,
                                           const u32* __restrict__ scmax, float* __restrict__ r,
                                           float* __restrict__ total, int N){
  int t=threadIdx.x; int c = t&(CC-1); int half = t>>7;
  float mx = fdec(*scmax);
  float acc=0.f, et=0.f;
  for(int n=blockIdx.x*2+half; n<N; n+=gridDim.x*2){
    float e = expf(sc[n]-mx);
    acc += e*xh[(size_t)n*CC+c];
    et += (c==0)? e : 0.f;
  }
  __shared__ float sacc[256];
  __shared__ float set_[2];
  sacc[t]=acc;
  if(c==0) set_[half]=et;
  __syncthreads();
  if(t<CC) atomicAdd(&r[t], sacc[t]+sacc[t+CC]);
  if(t==0) atomicAdd(total, set_[0]+set_[1]);
}

__global__ void k_finalize(const float* __restrict__ hS, const float* __restrict__ r,
                           const float* __restrict__ total, float* __restrict__ qstar){
  int t=threadIdx.x;
  if(t<CC) qstar[t]=hS[t];
  else if(t<2*CC) qstar[t]=r[t-CC]/total[0];
}

// ---------------- output MLP ----------------
__global__ __launch_bounds__(256) void k_out(
  const float* __restrict__ qstar, const float* __restrict__ vvec,
  const float* __restrict__ w1, const float* __restrict__ b1,
  const float* __restrict__ w2, const float* __restrict__ b2,
  const float* __restrict__ w3, const float* __restrict__ b3, float* __restrict__ out)
{
  __shared__ float comb[3*CC];
  __shared__ float o1[CC];
  __shared__ float o2[64];
  int t=threadIdx.x;
  if(t<2*CC) comb[t]=qstar[t];
  if(t<CC) comb[2*CC+t]=vvec[t];
  __syncthreads();
  if(t<CC){
    float a=b1[t];
    for(int j=0;j<3*CC;j++) a += comb[j]*w1[j*CC+t];
    o1[t]=fmaxf(a,0.f);
  }
  __syncthreads();
  if(t<64){
    float a=b2[t];
    for(int j=0;j<CC;j++) a += o1[j]*w2[j*64+t];
    o2[t]=fmaxf(a,0.f);
  }
  __syncthreads();
  {
    float a=b3[t];
    for(int j=0;j<64;j++) a += o2[j]*w3[j*256+t];
    out[t]=fmaxf(a,0.f);
  }
}

extern "C" void kernel_launch(void* const* d_in, const int* in_sizes, int n_in,
                              void* d_out, int out_size, void* d_ws, size_t ws_size,
                              hipStream_t stream){
  (void)n_in; (void)out_size; (void)ws_size;
  const float* x        = (const float*)d_in[0];
  const int*   eidx     = (const int*)  d_in[1];
  const float* edge_attr= (const float*)d_in[2];
  const float* vnf      = (const float*)d_in[3];
  const float* w_node   = (const float*)d_in[4];
  const float* b_node   = (const float*)d_in[5];
  const float* w_ee     = (const float*)d_in[6];
  const float* b_ee     = (const float*)d_in[7];
  const float* w_ep     = (const float*)d_in[8];
  const float* b_ep     = (const float*)d_in[9];
  const float* w_vnf    = (const float*)d_in[10];
  const float* b_vnf    = (const float*)d_in[11];
  const float* attn_w1  = (const float*)d_in[12];
  const float* attn_b1  = (const float*)d_in[13];
  const float* attn_w2  = (const float*)d_in[14];
  const float* attn_b2  = (const float*)d_in[15];
  const float* attn_w3  = (const float*)d_in[16];
  const float* attn_b3  = (const float*)d_in[17];
  const float* gat_w    = (const float*)d_in[18];
  const float* att_src  = (const float*)d_in[19];
  const float* att_dst  = (const float*)d_in[20];
  const float* gat_we   = (const float*)d_in[21];
  const float* att_e    = (const float*)d_in[22];
  const float* gat_b    = (const float*)d_in[23];
  const float* ln_g     = (const float*)d_in[24];
  const float* ln_b     = (const float*)d_in[25];
  const float* venc_w1  = (const float*)d_in[26];
  const float* venc_b1  = (const float*)d_in[27];
  const float* venc_w2  = (const float*)d_in[28];
  const float* venc_b2  = (const float*)d_in[29];
  const float* lstm_wih = (const float*)d_in[30];
  const float* lstm_whh = (const float*)d_in[31];
  const float* lstm_bih = (const float*)d_in[32];
  const float* lstm_bhh = (const float*)d_in[33];
  const float* out_w1   = (const float*)d_in[34];
  const float* out_b1   = (const float*)d_in[35];
  const float* out_w2   = (const float*)d_in[36];
  const float* out_b2   = (const float*)d_in[37];
  const float* out_w3   = (const float*)d_in[38];
  const float* out_b3   = (const float*)d_in[39];

  const int N = in_sizes[0]/8;
  const int E = in_sizes[1]/2;
  const int* srcA = eidx;
  const int* dstA = eidx + E;

  char* wp = (char*)d_ws;
  auto alloc = [&](size_t bytes)->void*{ void* p=(void*)wp; wp += (bytes+255)&~(size_t)255; return p; };
  float* xh    = (float*)alloc((size_t)N*CC*4);
  float* sbuf  = (float*)alloc((size_t)N*CC*HH*4);
  float* a_e   = (float*)alloc((size_t)LL*E*HH*4);
  float* asrc  = (float*)alloc((size_t)N*HH*4);
  float* adst  = (float*)alloc((size_t)N*HH*4);
  int* counts  = (int*)alloc((size_t)N*4);
  int* offsets = (int*)alloc((size_t)(N+1)*4);
  int* cursor  = (int*)alloc((size_t)N*4);
  int* elist   = (int*)alloc((size_t)E*4);
  float* sc    = (float*)alloc((size_t)N*4);
  float* wattS = (float*)alloc((size_t)LL*CC*HH*4);
  float* wattD = (float*)alloc((size_t)LL*CC*HH*4);
  float* wattE = (float*)alloc((size_t)LL*CC*HH*4);
  float* We    = (float*)alloc(4*CC*4);
  float* be    = (float*)alloc(CC*4);
  float* vemb  = (float*)alloc(CC*4);
  float* Wh1   = (float*)alloc(4*CC*4);
  float* bh1   = (float*)alloc(CC*4);
  float* aelin = (float*)alloc(48*4);
  float* aebias= (float*)alloc(12*4);
  float* Wbig  = (float*)alloc((size_t)LL*HH*CC*CC*4);
  float* vvec  = (float*)alloc(CC*4);
  float* lbuf  = (float*)alloc(4*CC*4);
  float* hS=lbuf; float* cS=lbuf+CC; float* qstar=lbuf+2*CC;
  float* s2s   = (float*)alloc(130*4);

  k_att_collapse<<<6,256,0,stream>>>(gat_w, att_src, wattS);
  k_att_collapse<<<6,256,0,stream>>>(gat_w, att_dst, wattD);
  k_att_collapse<<<6,256,0,stream>>>(gat_we, att_e, wattE);
  k_We<<<2,256,0,stream>>>(w_ee, w_ep, We);
  k_be_vemb<<<1,256,0,stream>>>(b_ee, w_ep, b_ep, vnf, w_vnf, b_vnf, be, vemb);
  k_h1eff<<<3,256,0,stream>>>(We, be, vemb, attn_w1, attn_b1, Wh1, bh1);
  k_aelin<<<1,64,0,stream>>>(We, be, wattE, aelin, aebias);
  k_wbig<<<(LL*HH*CC*CC+255)/256,256,0,stream>>>(gat_w, Wbig);
  k_vvec<<<1,CC,0,stream>>>(vnf, venc_w1, venc_b1, venc_w2, venc_b2, vvec);
  k_node_embed<<<(N*CC+255)/256,256,0,stream>>>(x, w_node, b_node, xh, N);

  hipMemsetAsync(counts, 0, (size_t)N*4, stream);
  k_count<<<(E+255)/256,256,0,stream>>>(dstA, counts, E);
  k_scan<<<1,1024,0,stream>>>(counts, offsets, N);
  hipMemsetAsync(cursor, 0, (size_t)N*4, stream);
  k_fill<<<(E+255)/256,256,0,stream>>>(dstA, offsets, cursor, elist, E);

  k_edge_attn<<<(E+63)/64,256,0,stream>>>(edge_attr, Wh1, bh1, attn_w2, attn_b2, attn_w3, attn_b3, aelin, aebias, a_e, E);

  for(int l=0;l<LL;l++){
    k_node_ad<<<(N*8+255)/256,256,0,stream>>>(xh, wattS+(size_t)l*CC*HH, wattD+(size_t)l*CC*HH, asrc, adst, N);
    k_aggregate<<<(N+3)/4,256,0,stream>>>(xh, srcA, a_e+(size_t)l*E*HH, asrc, adst, offsets, elist, sbuf, N);
    k_gemm_ln<<<(N+GR-1)/GR,256,0,stream>>>(sbuf, Wbig+(size_t)l*HH*CC*CC, gat_b+(size_t)l*CC,
                                            ln_g+(size_t)l*CC, ln_b+(size_t)l*CC, xh, N);
  }

  hipMemsetAsync(lbuf, 0, 4*CC*4, stream);
  for(int it=0; it<3; ++it){
    k_lstm<<<1,512,0,stream>>>(lstm_wih, lstm_whh, lstm_bih, lstm_bhh, qstar, hS, cS);
    hipMemsetAsync(s2s, 0, 130*4, stream);
    k_scores<<<512,256,0,stream>>>(xh, hS, sc, (u32*)s2s, N);
    k_r<<<512,256,0,stream>>>(xh, sc, (u32*)s2s, s2s+2, s2s+1, N);
    k_finalize<<<1,256,0,stream>>>(hS, s2s+2, s2s+1, qstar);
  }

  k_out<<<1,256,0,stream>>>(qstar, vvec, out_w1, out_b1, out_w2, out_b2, out_w3, out_b3, (float*)d_out);
}

// Round 4
// 901.226 us; speedup vs baseline: 1.2926x; 1.1779x over previous
//
#include <hip/hip_runtime.h>
#include <math.h>

#define CC 128
#define HH 4
#define LL 3
#define LNEPS 1e-5f

typedef unsigned int u32;
typedef unsigned short ushort;
typedef float f32x16 __attribute__((ext_vector_type(16)));
typedef __bf16 bf16x8 __attribute__((ext_vector_type(8)));
union Frag { uint4 q; bf16x8 b; };

__device__ __forceinline__ u32 fenc(float f){ u32 u=__float_as_uint(f); return (u&0x80000000u)? ~u : (u|0x80000000u); }
__device__ __forceinline__ float fdec(u32 u){ return (u&0x80000000u)? __uint_as_float(u&0x7FFFFFFFu) : __uint_as_float(~u); }
__device__ __forceinline__ ushort bf16rne(float x){ u32 u=__float_as_uint(x); return (ushort)((u + 0x7FFF + ((u>>16)&1))>>16); }
__device__ __forceinline__ float bf2f(ushort h){ return __uint_as_float(((u32)h)<<16); }

// ---------------- tiny precompute kernels ----------------

__global__ void k_att_collapse(const float* __restrict__ W, const float* __restrict__ att, float* __restrict__ out){
  int idx = blockIdx.x*blockDim.x + threadIdx.x;
  if(idx >= LL*CC*HH) return;
  int h = idx % HH; int k = (idx/HH)%CC; int l = idx/(HH*CC);
  const float* w = W + ((size_t)(l*CC+k))*(HH*CC) + h*CC;
  const float* a = att + (size_t)(l*HH+h)*CC;
  float s=0.f;
  for(int c=0;c<CC;c++) s += w[c]*a[c];
  out[idx] = s;
}

__global__ void k_We(const float* __restrict__ w_ee, const float* __restrict__ w_ep, float* __restrict__ We){
  int idx = blockIdx.x*blockDim.x + threadIdx.x;
  if(idx >= 4*CC) return;
  int c = idx & (CC-1); int k = idx >> 7;
  float s=0.f;
  for(int m=0;m<CC;m++) s += w_ee[k*CC+m]*w_ep[m*CC+c];
  We[idx]=s;
}

__global__ void k_be_vemb(const float* __restrict__ b_ee, const float* __restrict__ w_ep, const float* __restrict__ b_ep,
                          const float* __restrict__ vnf, const float* __restrict__ w_vnf, const float* __restrict__ b_vnf,
                          float* __restrict__ be, float* __restrict__ vemb){
  int t = threadIdx.x;
  if(t<CC){
    float s=b_ep[t];
    for(int m=0;m<CC;m++) s += b_ee[m]*w_ep[m*CC+t];
    be[t]=s;
  } else if(t<2*CC){
    int c=t-CC;
    float s=b_vnf[c];
    for(int j=0;j<6;j++) s += vnf[j]*w_vnf[j*CC+c];
    vemb[c]=s;
  }
}

__global__ void k_h1eff(const float* __restrict__ We, const float* __restrict__ be, const float* __restrict__ vemb,
                        const float* __restrict__ w1, const float* __restrict__ b1,
                        float* __restrict__ Wh1, float* __restrict__ bh1){
  int idx = blockIdx.x*blockDim.x + threadIdx.x;
  if(idx < 4*CC){
    int c = idx & (CC-1); int k = idx>>7;
    float s=0.f;
    for(int m=0;m<CC;m++) s += We[k*CC+m]*w1[m*CC+c];
    Wh1[idx]=s;
  } else if(idx < 5*CC){
    int c = idx - 4*CC;
    float s=b1[c];
    for(int m=0;m<CC;m++) s += be[m]*w1[m*CC+c];
    for(int j=0;j<CC;j++) s += vemb[j]*w1[(CC+j)*CC+c];
    bh1[c]=s;
  }
}

__global__ void k_aelin(const float* __restrict__ We, const float* __restrict__ be, const float* __restrict__ wattE,
                        float* __restrict__ aelin, float* __restrict__ aebias){
  int t = threadIdx.x;
  if(t<48){
    int l=t>>4, k=(t>>2)&3, h=t&3;
    float s=0.f;
    for(int m=0;m<CC;m++) s += We[k*CC+m]*wattE[(size_t)(l*CC+m)*HH+h];
    aelin[t]=s;
  } else if(t<60){
    int i=t-48; int l=i>>2, h=i&3;
    float s=0.f;
    for(int m=0;m<CC;m++) s += be[m]*wattE[(size_t)(l*CC+m)*HH+h];
    aebias[i]=s;
  }
}

// split + transpose + MFMA-tile W: B'[l][(c/32)*64 + hk/8][c%32][hk%8] = gat_w[l][k][h*128+c]*0.25
__global__ void k_wsplit(const float* __restrict__ gat_w, ushort* __restrict__ BHT, ushort* __restrict__ BLT){
  int idx = blockIdx.x*blockDim.x + threadIdx.x;
  if(idx >= LL*512*CC) return;
  int l = idx >> 16;
  int r = idx & 65535;
  int hk = r >> 7;
  int c  = r & 127;
  int k = hk & 127, h = hk >> 7;
  float v = gat_w[((size_t)(l*CC + k))*(HH*CC) + h*CC + c] * 0.25f;
  ushort hi = bf16rne(v);
  ushort lo = bf16rne(v - bf2f(hi));
  size_t pos = (size_t)l*65536 + ((size_t)(c>>5)*64 + (hk>>3))*256 + (size_t)((c&31)*8 + (hk&7));
  BHT[pos]=hi; BLT[pos]=lo;
}

__global__ void k_vvec(const float* __restrict__ vnf, const float* __restrict__ w1, const float* __restrict__ b1,
                       const float* __restrict__ w2, const float* __restrict__ b2, float* __restrict__ v){
  __shared__ float hv[CC];
  int t=threadIdx.x;
  float s=b1[t];
  for(int j=0;j<6;j++) s += vnf[j]*w1[j*CC+t];
  hv[t]=fmaxf(s,0.f);
  __syncthreads();
  float o=b2[t];
  for(int j=0;j<CC;j++) o += hv[j]*w2[j*CC+t];
  v[t]=o;
}

// ---------------- node embedding ----------------
__global__ void k_node_embed(const float* __restrict__ x, const float* __restrict__ w, const float* __restrict__ b,
                             float* __restrict__ xh, int N){
  int idx=blockIdx.x*blockDim.x+threadIdx.x;
  if(idx>=N*CC) return;
  int c=idx&(CC-1); int n=idx>>7;
  const float* xr = x+(size_t)n*8;
  float s=b[c];
  #pragma unroll
  for(int k=0;k<8;k++) s += xr[k]*w[k*CC+c];
  xh[idx]=s;
}

// ---------------- CSR by dst ----------------
__global__ void k_count(const int* __restrict__ dst, int* __restrict__ counts, int E){
  int e=blockIdx.x*blockDim.x+threadIdx.x;
  if(e<E) atomicAdd(&counts[dst[e]],1);
}

__global__ __launch_bounds__(1024) void k_scan(const int* __restrict__ counts, int* __restrict__ offsets, int N){
  __shared__ int sv[1024];
  int t=threadIdx.x;
  int per=(N+1023)/1024;
  int b=t*per; int e=b+per; if(e>N)e=N; if(b>N)b=N;
  int ssum=0;
  for(int i=b;i<e;i++) ssum+=counts[i];
  sv[t]=ssum;
  __syncthreads();
  for(int off=1;off<1024;off<<=1){
    int add = (t>=off)? sv[t-off]:0;
    __syncthreads();
    sv[t]+=add;
    __syncthreads();
  }
  int run = sv[t]-ssum;
  for(int i=b;i<e;i++){ offsets[i]=run; run+=counts[i]; }
  if(t==1023) offsets[N]=sv[1023];
}

__global__ void k_fill(const int* __restrict__ dst, const int* __restrict__ offsets, int* __restrict__ cursor,
                       int* __restrict__ elist, int E){
  int e=blockIdx.x*blockDim.x+threadIdx.x;
  if(e<E){ int d=dst[e]; int pos=atomicAdd(&cursor[d],1); elist[offsets[d]+pos]=e; }
}

// ---------------- fused edge-attention MLP -> a_e[l][e][h] (64-edge tile GEMM) ----------------
__global__ __launch_bounds__(256) void k_edge_attn(
    const float* __restrict__ edge_attr,
    const float* __restrict__ Wh1, const float* __restrict__ bh1,
    const float* __restrict__ attn_w2, const float* __restrict__ attn_b2,
    const float* __restrict__ attn_w3, const float* __restrict__ attn_b3,
    const float* __restrict__ aelin, const float* __restrict__ aebias,
    float* __restrict__ a_e, int E)
{
  __shared__ float s_w2[CC*64];
  __shared__ float s_h1t[64*64];
  __shared__ float s_eat[4*64];
  __shared__ float s_wh1t[CC*4];
  __shared__ float s_bh1[CC];
  __shared__ float s_b2[64];
  __shared__ float s_w3[64];
  __shared__ float s_lin[48];
  __shared__ float s_lbias[12];
  int t = threadIdx.x;
  for(int i=t;i<CC*64;i+=256) s_w2[i]=attn_w2[i];
  for(int i=t;i<CC*4;i+=256){ int c=i>>2, k=i&3; s_wh1t[i]=Wh1[k*CC+c]; }
  if(t<CC) s_bh1[t]=bh1[t];
  else if(t<CC+64) s_b2[t-CC]=attn_b2[t-CC];
  else if(t<CC+128) s_w3[t-CC-64]=attn_w3[t-CC-64];
  if(t<48) s_lin[t]=aelin[t];
  else if(t<60) s_lbias[t-48]=aebias[t-48];
  float b3v = attn_b3[0];
  int e0 = blockIdx.x*64;
  if(t<64){
    int e=e0+t;
    float4 v = (e<E)? *(const float4*)&edge_attr[(size_t)e*4] : make_float4(0.f,0.f,0.f,0.f);
    s_eat[t]=v.x; s_eat[64+t]=v.y; s_eat[128+t]=v.z; s_eat[192+t]=v.w;
  }
  int eg=t>>4, og=t&15;
  float acc[4][4];
  #pragma unroll
  for(int i=0;i<4;i++){ acc[i][0]=0.f; acc[i][1]=0.f; acc[i][2]=0.f; acc[i][3]=0.f; }
  for(int half=0;half<2;half++){
    __syncthreads();
    for(int i=t;i<64*64;i+=256){
      int kl=i>>6, e=i&63, k=half*64+kl;
      float4 w = *(const float4*)&s_wh1t[k*4];
      float v = s_bh1[k] + s_eat[e]*w.x + s_eat[64+e]*w.y + s_eat[128+e]*w.z + s_eat[192+e]*w.w;
      s_h1t[i] = fmaxf(v,0.f);
    }
    __syncthreads();
    const float* w2h = s_w2 + half*4096;
    #pragma unroll 8
    for(int k=0;k<64;k++){
      float4 a = *(const float4*)&s_h1t[k*64 + eg*4];
      float4 b = *(const float4*)&w2h[k*64 + og*4];
      acc[0][0]+=a.x*b.x; acc[0][1]+=a.x*b.y; acc[0][2]+=a.x*b.z; acc[0][3]+=a.x*b.w;
      acc[1][0]+=a.y*b.x; acc[1][1]+=a.y*b.y; acc[1][2]+=a.y*b.z; acc[1][3]+=a.y*b.w;
      acc[2][0]+=a.z*b.x; acc[2][1]+=a.z*b.y; acc[2][2]+=a.z*b.z; acc[2][3]+=a.z*b.w;
      acc[3][0]+=a.w*b.x; acc[3][1]+=a.w*b.y; acc[3][2]+=a.w*b.z; acc[3][3]+=a.w*b.w;
    }
  }
  float4 b2v = *(const float4*)&s_b2[og*4];
  float4 w3v = *(const float4*)&s_w3[og*4];
  float att[4];
  #pragma unroll
  for(int i=0;i<4;i++){
    float p = fmaxf(acc[i][0]+b2v.x,0.f)*w3v.x + fmaxf(acc[i][1]+b2v.y,0.f)*w3v.y
            + fmaxf(acc[i][2]+b2v.z,0.f)*w3v.z + fmaxf(acc[i][3]+b2v.w,0.f)*w3v.w;
    #pragma unroll
    for(int off=1;off<16;off<<=1) p += __shfl_xor(p,off);
    att[i] = 1.f/(1.f+expf(-(p+b3v)));
  }
  if(og<12){
    int l=og>>2, h=og&3;
    float w0=s_lin[l*16+h], w1=s_lin[l*16+4+h], w2x=s_lin[l*16+8+h], w3x=s_lin[l*16+12+h];
    float lb=s_lbias[l*4+h];
    #pragma unroll
    for(int i=0;i<4;i++){
      int el=eg*4+i; int e=e0+el;
      if(e<E){
        float v = s_eat[el]*w0 + s_eat[64+el]*w1 + s_eat[128+el]*w2x + s_eat[192+el]*w3x + lb;
        a_e[((size_t)l*E+e)*4+h] = att[i]*v;
      }
    }
  }
}

// ---------------- per-node attention logits ----------------
__global__ void k_node_ad(const float* __restrict__ xh, const float* __restrict__ wS, const float* __restrict__ wD,
                          float* __restrict__ asrc, float* __restrict__ adst, int N){
  int idx = blockIdx.x*blockDim.x + threadIdx.x;
  if(idx >= N*8) return;
  int o = idx & 7; int n = idx >> 3;
  const float* w = ((o<4)? wS : wD) + (o&3);
  const float* xr = xh + (size_t)n*CC;
  float s=0.f;
  for(int k=0;k<CC;k++) s += xr[k]*w[(size_t)k*HH];
  ((o<4)? asrc : adst)[n*4+(o&3)] = s;
}

// ---------------- per-dst GAT aggregation -> hi/lo bf16 MFMA-tiled sbuf ----------------
__global__ __launch_bounds__(256) void k_aggregate(
    const float* __restrict__ xh, const int* __restrict__ srcArr,
    const float* __restrict__ aeL, const float* __restrict__ asrc, const float* __restrict__ adst,
    const int* __restrict__ offsets, const int* __restrict__ elist,
    ushort* __restrict__ sH, ushort* __restrict__ sL, int N)
{
  int wave = threadIdx.x>>6, lane = threadIdx.x&63;
  int n = blockIdx.x*4+wave;
  if(n>=N) return;
  int beg = offsets[n];
  int deg = offsets[n+1]-beg;
  const float4* ae4 = (const float4*)aeL;
  const float4* as4 = (const float4*)asrc;
  float4 ad = ((const float4*)adst)[n];
  float mx0=-1e30f,mx1=-1e30f,mx2=-1e30f,mx3=-1e30f;
  for(int base=0;base<deg;base+=64){
    int i=base+lane;
    if(i<deg){
      int e = elist[beg+i];
      float4 ae = ae4[e];
      float4 as = as4[srcArr[e]];
      float a0=as.x+ad.x+ae.x; a0=(a0>0.f)?a0:0.2f*a0;
      float a1=as.y+ad.y+ae.y; a1=(a1>0.f)?a1:0.2f*a1;
      float a2=as.z+ad.z+ae.z; a2=(a2>0.f)?a2:0.2f*a2;
      float a3=as.w+ad.w+ae.w; a3=(a3>0.f)?a3:0.2f*a3;
      mx0=fmaxf(mx0,a0); mx1=fmaxf(mx1,a1); mx2=fmaxf(mx2,a2); mx3=fmaxf(mx3,a3);
    }
  }
  #pragma unroll
  for(int o=32;o>=1;o>>=1){
    mx0=fmaxf(mx0,__shfl_xor(mx0,o));
    mx1=fmaxf(mx1,__shfl_xor(mx1,o));
    mx2=fmaxf(mx2,__shfl_xor(mx2,o));
    mx3=fmaxf(mx3,__shfl_xor(mx3,o));
  }
  float sm0=0,sm1=0,sm2=0,sm3=0;
  float acc0=0,acc1=0,acc2=0,acc3=0,acc4=0,acc5=0,acc6=0,acc7=0;
  for(int base=0;base<deg;base+=64){
    int i=base+lane;
    float ex0=0,ex1=0,ex2=0,ex3=0; int mysrc=0;
    if(i<deg){
      int e = elist[beg+i];
      mysrc = srcArr[e];
      float4 ae = ae4[e];
      float4 as = as4[mysrc];
      float a0=as.x+ad.x+ae.x; a0=(a0>0.f)?a0:0.2f*a0;
      float a1=as.y+ad.y+ae.y; a1=(a1>0.f)?a1:0.2f*a1;
      float a2=as.z+ad.z+ae.z; a2=(a2>0.f)?a2:0.2f*a2;
      float a3=as.w+ad.w+ae.w; a3=(a3>0.f)?a3:0.2f*a3;
      ex0=expf(a0-mx0); ex1=expf(a1-mx1); ex2=expf(a2-mx2); ex3=expf(a3-mx3);
      sm0+=ex0; sm1+=ex1; sm2+=ex2; sm3+=ex3;
    }
    int cnt = deg-base; if(cnt>64) cnt=64;
    for(int j=0;j<cnt;j++){
      int sr = __shfl(mysrc,j);
      float al0=__shfl(ex0,j), al1=__shfl(ex1,j), al2=__shfl(ex2,j), al3=__shfl(ex3,j);
      const float* xr = xh + (size_t)sr*CC;
      float x0 = xr[lane], x1 = xr[lane+64];
      acc0 += al0*x0; acc1 += al0*x1;
      acc2 += al1*x0; acc3 += al1*x1;
      acc4 += al2*x0; acc5 += al2*x1;
      acc6 += al3*x0; acc7 += al3*x1;
    }
  }
  #pragma unroll
  for(int o=32;o>=1;o>>=1){
    sm0+=__shfl_xor(sm0,o); sm1+=__shfl_xor(sm1,o); sm2+=__shfl_xor(sm2,o); sm3+=__shfl_xor(sm3,o);
  }
  float i0=1.f/(sm0+1e-16f), i1=1.f/(sm1+1e-16f), i2=1.f/(sm2+1e-16f), i3=1.f/(sm3+1e-16f);
  // hi/lo bf16 split, MFMA-tiled layout: pos = ((n/32)*64 + hk/8)*256 + (n%32)*8 + hk%8
  size_t rowbase = ((size_t)(n>>5))*64*256 + (size_t)((n&31)*8);
  auto put=[&](int hk, float v){
    ushort hi = bf16rne(v);
    ushort lo = bf16rne(v - bf2f(hi));
    size_t pos = rowbase + (size_t)(hk>>3)*256 + (hk&7);
    sH[pos]=hi; sL[pos]=lo;
  };
  put(lane, acc0*i0);      put(lane+64, acc1*i0);
  put(128+lane, acc2*i1);  put(128+lane+64, acc3*i1);
  put(256+lane, acc4*i2);  put(256+lane+64, acc5*i2);
  put(384+lane, acc6*i3);  put(384+lane+64, acc7*i3);
}

// ---------------- MFMA split-bf16 GEMM [N,512]@[512,128] + bias + LN + residual ----------------
// block = 2 waves (128 thr), BM=128: wave w owns rows [blk*128 + w*64, +64) x all 128 cols.
// 32x32x16 bf16 MFMA; D layout: col=lane&31, row=(reg&3)+8*(reg>>2)+4*(lane>>5)  [m74/m101]
__global__ __launch_bounds__(128) void k_gemm_ln_mfma(
    const ushort* __restrict__ AH, const ushort* __restrict__ AL,
    const ushort* __restrict__ BH, const ushort* __restrict__ BL,
    const float* __restrict__ bias, const float* __restrict__ lng, const float* __restrict__ lnb,
    float* __restrict__ xh, int N)
{
  int tid = threadIdx.x;
  int w = tid>>6, lane = tid&63;
  int rlane = lane&31, khalf = lane>>5;
  int rb0 = blockIdx.x*4 + w*2;          // row-block (32 rows) index; wave owns rb0, rb0+1
  f32x16 acc[2][4];
  #pragma unroll
  for(int b=0;b<2;b++)
    #pragma unroll
    for(int t=0;t<4;t++)
      #pragma unroll
      for(int j=0;j<16;j++) acc[b][t][j]=0.f;

  const size_t laneoff = (size_t)(rlane*8);
  for(int ks=0; ks<32; ++ks){
    int kq = ks*2 + khalf;
    Frag ah[2], al[2];
    #pragma unroll
    for(int b=0;b<2;b++){
      size_t base = (((size_t)(rb0+b)*64 + kq)<<8) + laneoff;
      ah[b].q = *(const uint4*)(AH + base);
      al[b].q = *(const uint4*)(AL + base);
    }
    #pragma unroll
    for(int t=0;t<4;t++){
      size_t bb = (((size_t)t*64 + kq)<<8) + laneoff;
      Frag bh, bl;
      bh.q = *(const uint4*)(BH + bb);
      bl.q = *(const uint4*)(BL + bb);
      #pragma unroll
      for(int b=0;b<2;b++){
        acc[b][t] = __builtin_amdgcn_mfma_f32_32x32x16_bf16(ah[b].b, bh.b, acc[b][t], 0,0,0);
        acc[b][t] = __builtin_amdgcn_mfma_f32_32x32x16_bf16(ah[b].b, bl.b, acc[b][t], 0,0,0);
        acc[b][t] = __builtin_amdgcn_mfma_f32_32x32x16_bf16(al[b].b, bh.b, acc[b][t], 0,0,0);
      }
    }
  }
  // epilogue: bias + LN + residual, all in registers
  float bias4[4], g4[4], eb4[4];
  #pragma unroll
  for(int t=0;t<4;t++){ int c=t*32+rlane; bias4[t]=bias[c]; g4[t]=lng[c]; eb4[t]=lnb[c]; }
  #pragma unroll
  for(int b=0;b<2;b++){
    #pragma unroll
    for(int reg=0; reg<16; ++reg){
      int rloc = (reg&3) + 8*(reg>>2) + 4*khalf;
      int grow = (rb0+b)*32 + rloc;
      float x0=acc[b][0][reg]+bias4[0];
      float x1=acc[b][1][reg]+bias4[1];
      float x2=acc[b][2][reg]+bias4[2];
      float x3=acc[b][3][reg]+bias4[3];
      float s = x0+x1+x2+x3;
      #pragma unroll
      for(int off=1; off<32; off<<=1) s += __shfl_xor(s, off);
      float mu = s*(1.f/CC);
      x0-=mu; x1-=mu; x2-=mu; x3-=mu;
      float q = x0*x0+x1*x1+x2*x2+x3*x3;
      #pragma unroll
      for(int off=1; off<32; off<<=1) q += __shfl_xor(q, off);
      float inv = rsqrtf(q*(1.f/CC)+LNEPS);
      if(grow < N){
        size_t gi = (size_t)grow*CC + rlane;
        xh[gi+ 0]  = x0*inv*g4[0] + eb4[0] + xh[gi+ 0];
        xh[gi+32]  = x1*inv*g4[1] + eb4[1] + xh[gi+32];
        xh[gi+64]  = x2*inv*g4[2] + eb4[2] + xh[gi+64];
        xh[gi+96]  = x3*inv*g4[3] + eb4[3] + xh[gi+96];
      }
    }
  }
}

// ---------------- Set2Set ----------------
__global__ __launch_bounds__(512) void k_lstm(const float* __restrict__ wih, const float* __restrict__ whh,
                    const float* __restrict__ bih, const float* __restrict__ bhh,
                    const float* __restrict__ qstar, float* __restrict__ hS, float* __restrict__ cS){
  __shared__ float sq[2*CC];
  __shared__ float sh[CC];
  __shared__ float sg[4*CC];
  int t=threadIdx.x;
  if(t<2*CC) sq[t]=qstar[t];
  else if(t<3*CC) sh[t-2*CC]=hS[t-2*CC];
  __syncthreads();
  float a=bih[t]+bhh[t];
  const float* wr = wih + (size_t)t*2*CC;
  for(int j=0;j<2*CC;j++) a += wr[j]*sq[j];
  const float* hr = whh + (size_t)t*CC;
  for(int j=0;j<CC;j++) a += hr[j]*sh[j];
  sg[t]=a;
  __syncthreads();
  if(t<CC){
    float gi=sg[t], gf=sg[CC+t], gg=sg[2*CC+t], go=sg[3*CC+t];
    float c = 1.f/(1.f+expf(-gf))*cS[t] + 1.f/(1.f+expf(-gi))*tanhf(gg);
    float h = 1.f/(1.f+expf(-go))*tanhf(c);
    cS[t]=c; hS[t]=h;
  }
}

__global__ __launch_bounds__(256) void k_scores(const float* __restrict__ xh, const float* __restrict__ q,
                                                float* __restrict__ sc, u32* __restrict__ scmax, int N){
  int t=threadIdx.x; int wave=t>>6, lane=t&63;
  float q0=q[lane], q1=q[lane+64];
  float wmax=-1e30f;
  for(int n=blockIdx.x*4+wave; n<N; n+=gridDim.x*4){
    const float* xr = xh+(size_t)n*CC;
    float v = xr[lane]*q0 + xr[lane+64]*q1;
    #pragma unroll
    for(int o=32;o>=1;o>>=1) v += __shfl_xor(v,o);
    if(lane==0) sc[n]=v;
    wmax = fmaxf(wmax,v);
  }
  __shared__ float sm[4];
  if(lane==0) sm[wave]=wmax;
  __syncthreads();
  if(t==0){
    float m = fmaxf(fmaxf(sm[0],sm[1]),fmaxf(sm[2],sm[3]));
    atomicMax(scmax, fenc(m));
  }
}

__global__ __launch_bounds__(256) void k_r(const float* __restrict__ xh, const float* __restrict__ sc,
                                           const u32* __restrict__ scmax, float* __restrict__ r,
                                           float* __restrict__ total, int N){
  int t=threadIdx.x; int c = t&(CC-1); int half = t>>7;
  float mx = fdec(*scmax);
  float acc=0.f, et=0.f;
  for(int n=blockIdx.x*2+half; n<N; n+=gridDim.x*2){
    float e = expf(sc[n]-mx);
    acc += e*xh[(size_t)n*CC+c];
    et += (c==0)? e : 0.f;
  }
  __shared__ float sacc[256];
  __shared__ float set_[2];
  sacc[t]=acc;
  if(c==0) set_[half]=et;
  __syncthreads();
  if(t<CC) atomicAdd(&r[t], sacc[t]+sacc[t+CC]);
  if(t==0) atomicAdd(total, set_[0]+set_[1]);
}

__global__ void k_finalize(const float* __restrict__ hS, const float* __restrict__ r,
                           const float* __restrict__ total, float* __restrict__ qstar){
  int t=threadIdx.x;
  if(t<CC) qstar[t]=hS[t];
  else if(t<2*CC) qstar[t]=r[t-CC]/total[0];
}

// ---------------- output MLP ----------------
__global__ __launch_bounds__(256) void k_out(
  const float* __restrict__ qstar, const float* __restrict__ vvec,
  const float* __restrict__ w1, const float* __restrict__ b1,
  const float* __restrict__ w2, const float* __restrict__ b2,
  const float* __restrict__ w3, const float* __restrict__ b3, float* __restrict__ out)
{
  __shared__ float comb[3*CC];
  __shared__ float o1[CC];
  __shared__ float o2[64];
  int t=threadIdx.x;
  if(t<2*CC) comb[t]=qstar[t];
  if(t<CC) comb[2*CC+t]=vvec[t];
  __syncthreads();
  if(t<CC){
    float a=b1[t];
    for(int j=0;j<3*CC;j++) a += comb[j]*w1[j*CC+t];
    o1[t]=fmaxf(a,0.f);
  }
  __syncthreads();
  if(t<64){
    float a=b2[t];
    for(int j=0;j<CC;j++) a += o1[j]*w2[j*64+t];
    o2[t]=fmaxf(a,0.f);
  }
  __syncthreads();
  {
    float a=b3[t];
    for(int j=0;j<64;j++) a += o2[j]*w3[j*256+t];
    out[t]=fmaxf(a,0.f);
  }
}

extern "C" void kernel_launch(void* const* d_in, const int* in_sizes, int n_in,
                              void* d_out, int out_size, void* d_ws, size_t ws_size,
                              hipStream_t stream){
  (void)n_in; (void)out_size; (void)ws_size;
  const float* x        = (const float*)d_in[0];
  const int*   eidx     = (const int*)  d_in[1];
  const float* edge_attr= (const float*)d_in[2];
  const float* vnf      = (const float*)d_in[3];
  const float* w_node   = (const float*)d_in[4];
  const float* b_node   = (const float*)d_in[5];
  const float* w_ee     = (const float*)d_in[6];
  const float* b_ee     = (const float*)d_in[7];
  const float* w_ep     = (const float*)d_in[8];
  const float* b_ep     = (const float*)d_in[9];
  const float* w_vnf    = (const float*)d_in[10];
  const float* b_vnf    = (const float*)d_in[11];
  const float* attn_w1  = (const float*)d_in[12];
  const float* attn_b1  = (const float*)d_in[13];
  const float* attn_w2  = (const float*)d_in[14];
  const float* attn_b2  = (const float*)d_in[15];
  const float* attn_w3  = (const float*)d_in[16];
  const float* attn_b3  = (const float*)d_in[17];
  const float* gat_w    = (const float*)d_in[18];
  const float* att_src  = (const float*)d_in[19];
  const float* att_dst  = (const float*)d_in[20];
  const float* gat_we   = (const float*)d_in[21];
  const float* att_e    = (const float*)d_in[22];
  const float* gat_b    = (const float*)d_in[23];
  const float* ln_g     = (const float*)d_in[24];
  const float* ln_b     = (const float*)d_in[25];
  const float* venc_w1  = (const float*)d_in[26];
  const float* venc_b1  = (const float*)d_in[27];
  const float* venc_w2  = (const float*)d_in[28];
  const float* venc_b2  = (const float*)d_in[29];
  const float* lstm_wih = (const float*)d_in[30];
  const float* lstm_whh = (const float*)d_in[31];
  const float* lstm_bih = (const float*)d_in[32];
  const float* lstm_bhh = (const float*)d_in[33];
  const float* out_w1   = (const float*)d_in[34];
  const float* out_b1   = (const float*)d_in[35];
  const float* out_w2   = (const float*)d_in[36];
  const float* out_b2   = (const float*)d_in[37];
  const float* out_w3   = (const float*)d_in[38];
  const float* out_b3   = (const float*)d_in[39];

  const int N = in_sizes[0]/8;
  const int E = in_sizes[1]/2;
  const int* srcA = eidx;
  const int* dstA = eidx + E;

  const int Npad = ((N+127)/128)*128;
  const size_t atile = (size_t)(Npad/32)*64*256;   // ushort elements per hi/lo array

  char* wp = (char*)d_ws;
  auto alloc = [&](size_t bytes)->void*{ void* p=(void*)wp; wp += (bytes+255)&~(size_t)255; return p; };
  float* xh    = (float*)alloc((size_t)N*CC*4);
  ushort* sbufH= (ushort*)alloc(atile*2);
  ushort* sbufL= (ushort*)alloc(atile*2);
  ushort* BHT  = (ushort*)alloc((size_t)LL*512*CC*2);
  ushort* BLT  = (ushort*)alloc((size_t)LL*512*CC*2);
  float* a_e   = (float*)alloc((size_t)LL*E*HH*4);
  float* asrc  = (float*)alloc((size_t)N*HH*4);
  float* adst  = (float*)alloc((size_t)N*HH*4);
  int* counts  = (int*)alloc((size_t)N*4);
  int* offsets = (int*)alloc((size_t)(N+1)*4);
  int* cursor  = (int*)alloc((size_t)N*4);
  int* elist   = (int*)alloc((size_t)E*4);
  float* sc    = (float*)alloc((size_t)N*4);
  float* wattS = (float*)alloc((size_t)LL*CC*HH*4);
  float* wattD = (float*)alloc((size_t)LL*CC*HH*4);
  float* wattE = (float*)alloc((size_t)LL*CC*HH*4);
  float* We    = (float*)alloc(4*CC*4);
  float* be    = (float*)alloc(CC*4);
  float* vemb  = (float*)alloc(CC*4);
  float* Wh1   = (float*)alloc(4*CC*4);
  float* bh1   = (float*)alloc(CC*4);
  float* aelin = (float*)alloc(48*4);
  float* aebias= (float*)alloc(12*4);
  float* vvec  = (float*)alloc(CC*4);
  float* lbuf  = (float*)alloc(4*CC*4);
  float* hS=lbuf; float* cS=lbuf+CC; float* qstar=lbuf+2*CC;
  float* s2s   = (float*)alloc(130*4);

  k_att_collapse<<<6,256,0,stream>>>(gat_w, att_src, wattS);
  k_att_collapse<<<6,256,0,stream>>>(gat_w, att_dst, wattD);
  k_att_collapse<<<6,256,0,stream>>>(gat_we, att_e, wattE);
  k_We<<<2,256,0,stream>>>(w_ee, w_ep, We);
  k_be_vemb<<<1,256,0,stream>>>(b_ee, w_ep, b_ep, vnf, w_vnf, b_vnf, be, vemb);
  k_h1eff<<<3,256,0,stream>>>(We, be, vemb, attn_w1, attn_b1, Wh1, bh1);
  k_aelin<<<1,64,0,stream>>>(We, be, wattE, aelin, aebias);
  k_wsplit<<<(LL*512*CC+255)/256,256,0,stream>>>(gat_w, BHT, BLT);
  k_vvec<<<1,CC,0,stream>>>(vnf, venc_w1, venc_b1, venc_w2, venc_b2, vvec);
  k_node_embed<<<(N*CC+255)/256,256,0,stream>>>(x, w_node, b_node, xh, N);

  hipMemsetAsync(counts, 0, (size_t)N*4, stream);
  k_count<<<(E+255)/256,256,0,stream>>>(dstA, counts, E);
  k_scan<<<1,1024,0,stream>>>(counts, offsets, N);
  hipMemsetAsync(cursor, 0, (size_t)N*4, stream);
  k_fill<<<(E+255)/256,256,0,stream>>>(dstA, offsets, cursor, elist, E);

  k_edge_attn<<<(E+63)/64,256,0,stream>>>(edge_attr, Wh1, bh1, attn_w2, attn_b2, attn_w3, attn_b3, aelin, aebias, a_e, E);

  for(int l=0;l<LL;l++){
    k_node_ad<<<(N*8+255)/256,256,0,stream>>>(xh, wattS+(size_t)l*CC*HH, wattD+(size_t)l*CC*HH, asrc, adst, N);
    k_aggregate<<<(N+3)/4,256,0,stream>>>(xh, srcA, a_e+(size_t)l*E*HH, asrc, adst, offsets, elist, sbufH, sbufL, N);
    k_gemm_ln_mfma<<<Npad/128,128,0,stream>>>(sbufH, sbufL,
                                              BHT+(size_t)l*512*CC, BLT+(size_t)l*512*CC,
                                              gat_b+(size_t)l*CC, ln_g+(size_t)l*CC, ln_b+(size_t)l*CC, xh, N);
  }

  hipMemsetAsync(lbuf, 0, 4*CC*4, stream);
  for(int it=0; it<3; ++it){
    k_lstm<<<1,512,0,stream>>>(lstm_wih, lstm_whh, lstm_bih, lstm_bhh, qstar, hS, cS);
    hipMemsetAsync(s2s, 0, 130*4, stream);
    k_scores<<<512,256,0,stream>>>(xh, hS, sc, (u32*)s2s, N);
    k_r<<<512,256,0,stream>>>(xh, sc, (u32*)s2s, s2s+2, s2s+1, N);
    k_finalize<<<1,256,0,stream>>>(hS, s2s+2, s2s+1, qstar);
  }

  k_out<<<1,256,0,stream>>>(qstar, vvec, out_w1, out_b1, out_w2, out_b2, out_w3, out_b3, (float*)d_out);
}

// Round 5
// 836.823 us; speedup vs baseline: 1.3920x; 1.0770x over previous
//
#include <hip/hip_runtime.h>
#include <math.h>

#define CC 128
#define HH 4
#define LL 3
#define LNEPS 1e-5f

typedef unsigned int u32;
typedef unsigned short ushort;
typedef float f32x16 __attribute__((ext_vector_type(16)));
typedef __bf16 bf16x8 __attribute__((ext_vector_type(8)));
union Frag { uint4 q; bf16x8 b; };

__device__ __forceinline__ u32 fenc(float f){ u32 u=__float_as_uint(f); return (u&0x80000000u)? ~u : (u|0x80000000u); }
__device__ __forceinline__ float fdec(u32 u){ return (u&0x80000000u)? __uint_as_float(u&0x7FFFFFFFu) : __uint_as_float(~u); }
__device__ __forceinline__ ushort bf16rne(float x){ u32 u=__float_as_uint(x); return (ushort)((u + 0x7FFF + ((u>>16)&1))>>16); }
__device__ __forceinline__ float bf2f(ushort h){ return __uint_as_float(((u32)h)<<16); }

// ---------------- tiny precompute kernels ----------------

__global__ void k_att_collapse(const float* __restrict__ W, const float* __restrict__ att, float* __restrict__ out){
  int idx = blockIdx.x*blockDim.x + threadIdx.x;
  if(idx >= LL*CC*HH) return;
  int h = idx % HH; int k = (idx/HH)%CC; int l = idx/(HH*CC);
  const float* w = W + ((size_t)(l*CC+k))*(HH*CC) + h*CC;
  const float* a = att + (size_t)(l*HH+h)*CC;
  float s=0.f;
  for(int c=0;c<CC;c++) s += w[c]*a[c];
  out[idx] = s;
}

__global__ void k_We(const float* __restrict__ w_ee, const float* __restrict__ w_ep, float* __restrict__ We){
  int idx = blockIdx.x*blockDim.x + threadIdx.x;
  if(idx >= 4*CC) return;
  int c = idx & (CC-1); int k = idx >> 7;
  float s=0.f;
  for(int m=0;m<CC;m++) s += w_ee[k*CC+m]*w_ep[m*CC+c];
  We[idx]=s;
}

__global__ void k_be_vemb(const float* __restrict__ b_ee, const float* __restrict__ w_ep, const float* __restrict__ b_ep,
                          const float* __restrict__ vnf, const float* __restrict__ w_vnf, const float* __restrict__ b_vnf,
                          float* __restrict__ be, float* __restrict__ vemb){
  int t = threadIdx.x;
  if(t<CC){
    float s=b_ep[t];
    for(int m=0;m<CC;m++) s += b_ee[m]*w_ep[m*CC+t];
    be[t]=s;
  } else if(t<2*CC){
    int c=t-CC;
    float s=b_vnf[c];
    for(int j=0;j<6;j++) s += vnf[j]*w_vnf[j*CC+c];
    vemb[c]=s;
  }
}

__global__ void k_h1eff(const float* __restrict__ We, const float* __restrict__ be, const float* __restrict__ vemb,
                        const float* __restrict__ w1, const float* __restrict__ b1,
                        float* __restrict__ Wh1, float* __restrict__ bh1){
  int idx = blockIdx.x*blockDim.x + threadIdx.x;
  if(idx < 4*CC){
    int c = idx & (CC-1); int k = idx>>7;
    float s=0.f;
    for(int m=0;m<CC;m++) s += We[k*CC+m]*w1[m*CC+c];
    Wh1[idx]=s;
  } else if(idx < 5*CC){
    int c = idx - 4*CC;
    float s=b1[c];
    for(int m=0;m<CC;m++) s += be[m]*w1[m*CC+c];
    for(int j=0;j<CC;j++) s += vemb[j]*w1[(CC+j)*CC+c];
    bh1[c]=s;
  }
}

__global__ void k_aelin(const float* __restrict__ We, const float* __restrict__ be, const float* __restrict__ wattE,
                        float* __restrict__ aelin, float* __restrict__ aebias){
  int t = threadIdx.x;
  if(t<48){
    int l=t>>4, k=(t>>2)&3, h=t&3;
    float s=0.f;
    for(int m=0;m<CC;m++) s += We[k*CC+m]*wattE[(size_t)(l*CC+m)*HH+h];
    aelin[t]=s;
  } else if(t<60){
    int i=t-48; int l=i>>2, h=i&3;
    float s=0.f;
    for(int m=0;m<CC;m++) s += be[m]*wattE[(size_t)(l*CC+m)*HH+h];
    aebias[i]=s;
  }
}

// split + transpose + MFMA-tile W: B'[l][(c/32)*64 + hk/8][c%32][hk%8] = gat_w[l][k][h*128+c]*0.25
__global__ void k_wsplit(const float* __restrict__ gat_w, ushort* __restrict__ BHT, ushort* __restrict__ BLT){
  int idx = blockIdx.x*blockDim.x + threadIdx.x;
  if(idx >= LL*512*CC) return;
  int l = idx >> 16;
  int r = idx & 65535;
  int hk = r >> 7;
  int c  = r & 127;
  int k = hk & 127, h = hk >> 7;
  float v = gat_w[((size_t)(l*CC + k))*(HH*CC) + h*CC + c] * 0.25f;
  ushort hi = bf16rne(v);
  ushort lo = bf16rne(v - bf2f(hi));
  size_t pos = (size_t)l*65536 + ((size_t)(c>>5)*64 + (hk>>3))*256 + (size_t)((c&31)*8 + (hk&7));
  BHT[pos]=hi; BLT[pos]=lo;
}

__global__ void k_vvec(const float* __restrict__ vnf, const float* __restrict__ w1, const float* __restrict__ b1,
                       const float* __restrict__ w2, const float* __restrict__ b2, float* __restrict__ v){
  __shared__ float hv[CC];
  int t=threadIdx.x;
  float s=b1[t];
  for(int j=0;j<6;j++) s += vnf[j]*w1[j*CC+t];
  hv[t]=fmaxf(s,0.f);
  __syncthreads();
  float o=b2[t];
  for(int j=0;j<CC;j++) o += hv[j]*w2[j*CC+t];
  v[t]=o;
}

// ---------------- node embedding ----------------
__global__ void k_node_embed(const float* __restrict__ x, const float* __restrict__ w, const float* __restrict__ b,
                             float* __restrict__ xh, int N){
  int idx=blockIdx.x*blockDim.x+threadIdx.x;
  if(idx>=N*CC) return;
  int c=idx&(CC-1); int n=idx>>7;
  const float* xr = x+(size_t)n*8;
  float s=b[c];
  #pragma unroll
  for(int k=0;k<8;k++) s += xr[k]*w[k*CC+c];
  xh[idx]=s;
}

// ---------------- CSR by dst (hierarchical scan) ----------------
__global__ void k_count(const int* __restrict__ dst, int* __restrict__ counts, int E){
  int e=blockIdx.x*blockDim.x+threadIdx.x;
  if(e<E) atomicAdd(&counts[dst[e]],1);
}

__global__ __launch_bounds__(256) void k_scan_blk(const int* __restrict__ counts, int* __restrict__ offsets,
                                                  int* __restrict__ bsum, int N){
  __shared__ int sv[256];
  int t=threadIdx.x; int i=blockIdx.x*256+t;
  int v = (i<N)? counts[i] : 0;
  sv[t]=v;
  __syncthreads();
  for(int off=1;off<256;off<<=1){
    int add = (t>=off)? sv[t-off]:0;
    __syncthreads();
    sv[t]+=add;
    __syncthreads();
  }
  if(i<N) offsets[i]=sv[t]-v;          // exclusive within block
  if(t==255) bsum[blockIdx.x]=sv[255]; // block total
}

__global__ __launch_bounds__(1024) void k_scan_top(int* __restrict__ bsum, int nb){
  __shared__ int sv[1024];
  int t=threadIdx.x;
  int v = (t<nb)? bsum[t] : 0;
  sv[t]=v;
  __syncthreads();
  for(int off=1;off<1024;off<<=1){
    int add = (t>=off)? sv[t-off]:0;
    __syncthreads();
    sv[t]+=add;
    __syncthreads();
  }
  if(t<nb) bsum[t]=sv[t]-v;            // exclusive block prefix
}

__global__ void k_scan_add(int* __restrict__ offsets, const int* __restrict__ bsum, int N, int E){
  int i=blockIdx.x*blockDim.x+threadIdx.x;
  if(i<N) offsets[i]+=bsum[i>>8];
  if(i==0) offsets[N]=E;
}

__global__ void k_fill(const int* __restrict__ dst, const int* __restrict__ offsets, int* __restrict__ cursor,
                       int* __restrict__ elist, int E){
  int e=blockIdx.x*blockDim.x+threadIdx.x;
  if(e<E){ int d=dst[e]; int pos=atomicAdd(&cursor[d],1); elist[offsets[d]+pos]=e; }
}

// ---------------- fused edge-attention MLP -> a_e[l][e][h] (64-edge tile GEMM) ----------------
__global__ __launch_bounds__(256) void k_edge_attn(
    const float* __restrict__ edge_attr,
    const float* __restrict__ Wh1, const float* __restrict__ bh1,
    const float* __restrict__ attn_w2, const float* __restrict__ attn_b2,
    const float* __restrict__ attn_w3, const float* __restrict__ attn_b3,
    const float* __restrict__ aelin, const float* __restrict__ aebias,
    float* __restrict__ a_e, int E)
{
  __shared__ float s_w2[CC*64];
  __shared__ float s_h1t[64*64];
  __shared__ float s_eat[4*64];
  __shared__ float s_wh1t[CC*4];
  __shared__ float s_bh1[CC];
  __shared__ float s_b2[64];
  __shared__ float s_w3[64];
  __shared__ float s_lin[48];
  __shared__ float s_lbias[12];
  int t = threadIdx.x;
  for(int i=t;i<CC*64;i+=256) s_w2[i]=attn_w2[i];
  for(int i=t;i<CC*4;i+=256){ int c=i>>2, k=i&3; s_wh1t[i]=Wh1[k*CC+c]; }
  if(t<CC) s_bh1[t]=bh1[t];
  else if(t<CC+64) s_b2[t-CC]=attn_b2[t-CC];
  else if(t<CC+128) s_w3[t-CC-64]=attn_w3[t-CC-64];
  if(t<48) s_lin[t]=aelin[t];
  else if(t<60) s_lbias[t-48]=aebias[t-48];
  float b3v = attn_b3[0];
  int e0 = blockIdx.x*64;
  if(t<64){
    int e=e0+t;
    float4 v = (e<E)? *(const float4*)&edge_attr[(size_t)e*4] : make_float4(0.f,0.f,0.f,0.f);
    s_eat[t]=v.x; s_eat[64+t]=v.y; s_eat[128+t]=v.z; s_eat[192+t]=v.w;
  }
  int eg=t>>4, og=t&15;
  float acc[4][4];
  #pragma unroll
  for(int i=0;i<4;i++){ acc[i][0]=0.f; acc[i][1]=0.f; acc[i][2]=0.f; acc[i][3]=0.f; }
  for(int half=0;half<2;half++){
    __syncthreads();
    for(int i=t;i<64*64;i+=256){
      int kl=i>>6, e=i&63, k=half*64+kl;
      float4 w = *(const float4*)&s_wh1t[k*4];
      float v = s_bh1[k] + s_eat[e]*w.x + s_eat[64+e]*w.y + s_eat[128+e]*w.z + s_eat[192+e]*w.w;
      s_h1t[i] = fmaxf(v,0.f);
    }
    __syncthreads();
    const float* w2h = s_w2 + half*4096;
    #pragma unroll 8
    for(int k=0;k<64;k++){
      float4 a = *(const float4*)&s_h1t[k*64 + eg*4];
      float4 b = *(const float4*)&w2h[k*64 + og*4];
      acc[0][0]+=a.x*b.x; acc[0][1]+=a.x*b.y; acc[0][2]+=a.x*b.z; acc[0][3]+=a.x*b.w;
      acc[1][0]+=a.y*b.x; acc[1][1]+=a.y*b.y; acc[1][2]+=a.y*b.z; acc[1][3]+=a.y*b.w;
      acc[2][0]+=a.z*b.x; acc[2][1]+=a.z*b.y; acc[2][2]+=a.z*b.z; acc[2][3]+=a.z*b.w;
      acc[3][0]+=a.w*b.x; acc[3][1]+=a.w*b.y; acc[3][2]+=a.w*b.z; acc[3][3]+=a.w*b.w;
    }
  }
  float4 b2v = *(const float4*)&s_b2[og*4];
  float4 w3v = *(const float4*)&s_w3[og*4];
  float att[4];
  #pragma unroll
  for(int i=0;i<4;i++){
    float p = fmaxf(acc[i][0]+b2v.x,0.f)*w3v.x + fmaxf(acc[i][1]+b2v.y,0.f)*w3v.y
            + fmaxf(acc[i][2]+b2v.z,0.f)*w3v.z + fmaxf(acc[i][3]+b2v.w,0.f)*w3v.w;
    #pragma unroll
    for(int off=1;off<16;off<<=1) p += __shfl_xor(p,off);
    att[i] = 1.f/(1.f+expf(-(p+b3v)));
  }
  if(og<12){
    int l=og>>2, h=og&3;
    float w0=s_lin[l*16+h], w1=s_lin[l*16+4+h], w2x=s_lin[l*16+8+h], w3x=s_lin[l*16+12+h];
    float lb=s_lbias[l*4+h];
    #pragma unroll
    for(int i=0;i<4;i++){
      int el=eg*4+i; int e=e0+el;
      if(e<E){
        float v = s_eat[el]*w0 + s_eat[64+el]*w1 + s_eat[128+el]*w2x + s_eat[192+el]*w3x + lb;
        a_e[((size_t)l*E+e)*4+h] = att[i]*v;
      }
    }
  }
}

// ---------------- per-node attention logits ----------------
__global__ void k_node_ad(const float* __restrict__ xh, const float* __restrict__ wS, const float* __restrict__ wD,
                          float* __restrict__ asrc, float* __restrict__ adst, int N){
  int idx = blockIdx.x*blockDim.x + threadIdx.x;
  if(idx >= N*8) return;
  int o = idx & 7; int n = idx >> 3;
  const float* w = ((o<4)? wS : wD) + (o&3);
  const float* xr = xh + (size_t)n*CC;
  float s=0.f;
  for(int k=0;k<CC;k++) s += xr[k]*w[(size_t)k*HH];
  ((o<4)? asrc : adst)[n*4+(o&3)] = s;
}

// ---------------- per-dst GAT aggregation -> hi/lo bf16 MFMA-tiled sbuf ----------------
__global__ __launch_bounds__(256) void k_aggregate(
    const float* __restrict__ xh, const int* __restrict__ srcArr,
    const float* __restrict__ aeL, const float* __restrict__ asrc, const float* __restrict__ adst,
    const int* __restrict__ offsets, const int* __restrict__ elist,
    ushort* __restrict__ sH, ushort* __restrict__ sL, int N)
{
  int wave = threadIdx.x>>6, lane = threadIdx.x&63;
  int n = blockIdx.x*4+wave;
  if(n>=N) return;
  int beg = offsets[n];
  int deg = offsets[n+1]-beg;
  const float4* ae4 = (const float4*)aeL;
  const float4* as4 = (const float4*)asrc;
  float4 ad = ((const float4*)adst)[n];
  float mx0=-1e30f,mx1=-1e30f,mx2=-1e30f,mx3=-1e30f;
  for(int base=0;base<deg;base+=64){
    int i=base+lane;
    if(i<deg){
      int e = elist[beg+i];
      float4 ae = ae4[e];
      float4 as = as4[srcArr[e]];
      float a0=as.x+ad.x+ae.x; a0=(a0>0.f)?a0:0.2f*a0;
      float a1=as.y+ad.y+ae.y; a1=(a1>0.f)?a1:0.2f*a1;
      float a2=as.z+ad.z+ae.z; a2=(a2>0.f)?a2:0.2f*a2;
      float a3=as.w+ad.w+ae.w; a3=(a3>0.f)?a3:0.2f*a3;
      mx0=fmaxf(mx0,a0); mx1=fmaxf(mx1,a1); mx2=fmaxf(mx2,a2); mx3=fmaxf(mx3,a3);
    }
  }
  #pragma unroll
  for(int o=32;o>=1;o>>=1){
    mx0=fmaxf(mx0,__shfl_xor(mx0,o));
    mx1=fmaxf(mx1,__shfl_xor(mx1,o));
    mx2=fmaxf(mx2,__shfl_xor(mx2,o));
    mx3=fmaxf(mx3,__shfl_xor(mx3,o));
  }
  float sm0=0,sm1=0,sm2=0,sm3=0;
  float acc0=0,acc1=0,acc2=0,acc3=0,acc4=0,acc5=0,acc6=0,acc7=0;
  for(int base=0;base<deg;base+=64){
    int i=base+lane;
    float ex0=0,ex1=0,ex2=0,ex3=0; int mysrc=0;
    if(i<deg){
      int e = elist[beg+i];
      mysrc = srcArr[e];
      float4 ae = ae4[e];
      float4 as = as4[mysrc];
      float a0=as.x+ad.x+ae.x; a0=(a0>0.f)?a0:0.2f*a0;
      float a1=as.y+ad.y+ae.y; a1=(a1>0.f)?a1:0.2f*a1;
      float a2=as.z+ad.z+ae.z; a2=(a2>0.f)?a2:0.2f*a2;
      float a3=as.w+ad.w+ae.w; a3=(a3>0.f)?a3:0.2f*a3;
      ex0=expf(a0-mx0); ex1=expf(a1-mx1); ex2=expf(a2-mx2); ex3=expf(a3-mx3);
      sm0+=ex0; sm1+=ex1; sm2+=ex2; sm3+=ex3;
    }
    int cnt = deg-base; if(cnt>64) cnt=64;
    for(int j=0;j<cnt;j++){
      int sr = __shfl(mysrc,j);
      float al0=__shfl(ex0,j), al1=__shfl(ex1,j), al2=__shfl(ex2,j), al3=__shfl(ex3,j);
      const float* xr = xh + (size_t)sr*CC;
      float x0 = xr[lane], x1 = xr[lane+64];
      acc0 += al0*x0; acc1 += al0*x1;
      acc2 += al1*x0; acc3 += al1*x1;
      acc4 += al2*x0; acc5 += al2*x1;
      acc6 += al3*x0; acc7 += al3*x1;
    }
  }
  #pragma unroll
  for(int o=32;o>=1;o>>=1){
    sm0+=__shfl_xor(sm0,o); sm1+=__shfl_xor(sm1,o); sm2+=__shfl_xor(sm2,o); sm3+=__shfl_xor(sm3,o);
  }
  float i0=1.f/(sm0+1e-16f), i1=1.f/(sm1+1e-16f), i2=1.f/(sm2+1e-16f), i3=1.f/(sm3+1e-16f);
  size_t rowbase = ((size_t)(n>>5))*64*256 + (size_t)((n&31)*8);
  auto put=[&](int hk, float v){
    ushort hi = bf16rne(v);
    ushort lo = bf16rne(v - bf2f(hi));
    size_t pos = rowbase + (size_t)(hk>>3)*256 + (hk&7);
    sH[pos]=hi; sL[pos]=lo;
  };
  put(lane, acc0*i0);      put(lane+64, acc1*i0);
  put(128+lane, acc2*i1);  put(128+lane+64, acc3*i1);
  put(256+lane, acc4*i2);  put(256+lane+64, acc5*i2);
  put(384+lane, acc6*i3);  put(384+lane+64, acc7*i3);
}

// ---------------- MFMA split-bf16 GEMM [N,512]@[512,128] + bias + LN + residual ----------------
__global__ __launch_bounds__(128) void k_gemm_ln_mfma(
    const ushort* __restrict__ AH, const ushort* __restrict__ AL,
    const ushort* __restrict__ BH, const ushort* __restrict__ BL,
    const float* __restrict__ bias, const float* __restrict__ lng, const float* __restrict__ lnb,
    float* __restrict__ xh, int N)
{
  int tid = threadIdx.x;
  int w = tid>>6, lane = tid&63;
  int rlane = lane&31, khalf = lane>>5;
  int rb0 = blockIdx.x*4 + w*2;
  f32x16 acc[2][4];
  #pragma unroll
  for(int b=0;b<2;b++)
    #pragma unroll
    for(int t=0;t<4;t++)
      #pragma unroll
      for(int j=0;j<16;j++) acc[b][t][j]=0.f;

  const size_t laneoff = (size_t)(rlane*8);
  for(int ks=0; ks<32; ++ks){
    int kq = ks*2 + khalf;
    Frag ah[2], al[2];
    #pragma unroll
    for(int b=0;b<2;b++){
      size_t base = (((size_t)(rb0+b)*64 + kq)<<8) + laneoff;
      ah[b].q = *(const uint4*)(AH + base);
      al[b].q = *(const uint4*)(AL + base);
    }
    #pragma unroll
    for(int t=0;t<4;t++){
      size_t bb = (((size_t)t*64 + kq)<<8) + laneoff;
      Frag bh, bl;
      bh.q = *(const uint4*)(BH + bb);
      bl.q = *(const uint4*)(BL + bb);
      #pragma unroll
      for(int b=0;b<2;b++){
        acc[b][t] = __builtin_amdgcn_mfma_f32_32x32x16_bf16(ah[b].b, bh.b, acc[b][t], 0,0,0);
        acc[b][t] = __builtin_amdgcn_mfma_f32_32x32x16_bf16(ah[b].b, bl.b, acc[b][t], 0,0,0);
        acc[b][t] = __builtin_amdgcn_mfma_f32_32x32x16_bf16(al[b].b, bh.b, acc[b][t], 0,0,0);
      }
    }
  }
  float bias4[4], g4[4], eb4[4];
  #pragma unroll
  for(int t=0;t<4;t++){ int c=t*32+rlane; bias4[t]=bias[c]; g4[t]=lng[c]; eb4[t]=lnb[c]; }
  #pragma unroll
  for(int b=0;b<2;b++){
    #pragma unroll
    for(int reg=0; reg<16; ++reg){
      int rloc = (reg&3) + 8*(reg>>2) + 4*khalf;
      int grow = (rb0+b)*32 + rloc;
      float x0=acc[b][0][reg]+bias4[0];
      float x1=acc[b][1][reg]+bias4[1];
      float x2=acc[b][2][reg]+bias4[2];
      float x3=acc[b][3][reg]+bias4[3];
      float s = x0+x1+x2+x3;
      #pragma unroll
      for(int off=1; off<32; off<<=1) s += __shfl_xor(s, off);
      float mu = s*(1.f/CC);
      x0-=mu; x1-=mu; x2-=mu; x3-=mu;
      float q = x0*x0+x1*x1+x2*x2+x3*x3;
      #pragma unroll
      for(int off=1; off<32; off<<=1) q += __shfl_xor(q, off);
      float inv = rsqrtf(q*(1.f/CC)+LNEPS);
      if(grow < N){
        size_t gi = (size_t)grow*CC + rlane;
        xh[gi+ 0]  = x0*inv*g4[0] + eb4[0] + xh[gi+ 0];
        xh[gi+32]  = x1*inv*g4[1] + eb4[1] + xh[gi+32];
        xh[gi+64]  = x2*inv*g4[2] + eb4[2] + xh[gi+64];
        xh[gi+96]  = x3*inv*g4[3] + eb4[3] + xh[gi+96];
      }
    }
  }
}

// ---------------- Set2Set ----------------
__global__ __launch_bounds__(512) void k_lstm(const float* __restrict__ wih, const float* __restrict__ whh,
                    const float* __restrict__ bih, const float* __restrict__ bhh,
                    const float* __restrict__ qstar, float* __restrict__ hS, float* __restrict__ cS){
  __shared__ float sq[2*CC];
  __shared__ float sh[CC];
  __shared__ float sg[4*CC];
  int t=threadIdx.x;
  if(t<2*CC) sq[t]=qstar[t];
  else if(t<3*CC) sh[t-2*CC]=hS[t-2*CC];
  __syncthreads();
  float a=bih[t]+bhh[t];
  const float* wr = wih + (size_t)t*2*CC;
  for(int j=0;j<2*CC;j++) a += wr[j]*sq[j];
  const float* hr = whh + (size_t)t*CC;
  for(int j=0;j<CC;j++) a += hr[j]*sh[j];
  sg[t]=a;
  __syncthreads();
  if(t<CC){
    float gi=sg[t], gf=sg[CC+t], gg=sg[2*CC+t], go=sg[3*CC+t];
    float c = 1.f/(1.f+expf(-gf))*cS[t] + 1.f/(1.f+expf(-gi))*tanhf(gg);
    float h = 1.f/(1.f+expf(-go))*tanhf(c);
    cS[t]=c; hS[t]=h;
  }
}

__global__ __launch_bounds__(256) void k_scores(const float* __restrict__ xh, const float* __restrict__ q,
                                                float* __restrict__ sc, u32* __restrict__ scmax, int N){
  int t=threadIdx.x; int wave=t>>6, lane=t&63;
  float q0=q[lane], q1=q[lane+64];
  float wmax=-1e30f;
  for(int n=blockIdx.x*4+wave; n<N; n+=gridDim.x*4){
    const float* xr = xh+(size_t)n*CC;
    float v = xr[lane]*q0 + xr[lane+64]*q1;
    #pragma unroll
    for(int o=32;o>=1;o>>=1) v += __shfl_xor(v,o);
    if(lane==0) sc[n]=v;
    wmax = fmaxf(wmax,v);
  }
  __shared__ float sm[4];
  if(lane==0) sm[wave]=wmax;
  __syncthreads();
  if(t==0){
    float m = fmaxf(fmaxf(sm[0],sm[1]),fmaxf(sm[2],sm[3]));
    atomicMax(scmax, fenc(m));
  }
}

__global__ __launch_bounds__(256) void k_r(const float* __restrict__ xh, const float* __restrict__ sc,
                                           const u32* __restrict__ scmax, float* __restrict__ r,
                                           float* __restrict__ total, int N){
  int t=threadIdx.x; int c = t&(CC-1); int half = t>>7;
  float mx = fdec(*scmax);
  float acc=0.f, et=0.f;
  for(int n=blockIdx.x*2+half; n<N; n+=gridDim.x*2){
    float e = expf(sc[n]-mx);
    acc += e*xh[(size_t)n*CC+c];
    et += (c==0)? e : 0.f;
  }
  __shared__ float sacc[256];
  __shared__ float set_[2];
  sacc[t]=acc;
  if(c==0) set_[half]=et;
  __syncthreads();
  if(t<CC) atomicAdd(&r[t], sacc[t]+sacc[t+CC]);
  if(t==0) atomicAdd(total, set_[0]+set_[1]);
}

__global__ void k_finalize(const float* __restrict__ hS, const float* __restrict__ r,
                           const float* __restrict__ total, float* __restrict__ qstar){
  int t=threadIdx.x;
  if(t<CC) qstar[t]=hS[t];
  else if(t<2*CC) qstar[t]=r[t-CC]/total[0];
}

// ---------------- output MLP ----------------
__global__ __launch_bounds__(256) void k_out(
  const float* __restrict__ qstar, const float* __restrict__ vvec,
  const float* __restrict__ w1, const float* __restrict__ b1,
  const float* __restrict__ w2, const float* __restrict__ b2,
  const float* __restrict__ w3, const float* __restrict__ b3, float* __restrict__ out)
{
  __shared__ float comb[3*CC];
  __shared__ float o1[CC];
  __shared__ float o2[64];
  int t=threadIdx.x;
  if(t<2*CC) comb[t]=qstar[t];
  if(t<CC) comb[2*CC+t]=vvec[t];
  __syncthreads();
  if(t<CC){
    float a=b1[t];
    for(int j=0;j<3*CC;j++) a += comb[j]*w1[j*CC+t];
    o1[t]=fmaxf(a,0.f);
  }
  __syncthreads();
  if(t<64){
    float a=b2[t];
    for(int j=0;j<CC;j++) a += o1[j]*w2[j*64+t];
    o2[t]=fmaxf(a,0.f);
  }
  __syncthreads();
  {
    float a=b3[t];
    for(int j=0;j<64;j++) a += o2[j]*w3[j*256+t];
    out[t]=fmaxf(a,0.f);
  }
}

extern "C" void kernel_launch(void* const* d_in, const int* in_sizes, int n_in,
                              void* d_out, int out_size, void* d_ws, size_t ws_size,
                              hipStream_t stream){
  (void)n_in; (void)out_size; (void)ws_size;
  const float* x        = (const float*)d_in[0];
  const int*   eidx     = (const int*)  d_in[1];
  const float* edge_attr= (const float*)d_in[2];
  const float* vnf      = (const float*)d_in[3];
  const float* w_node   = (const float*)d_in[4];
  const float* b_node   = (const float*)d_in[5];
  const float* w_ee     = (const float*)d_in[6];
  const float* b_ee     = (const float*)d_in[7];
  const float* w_ep     = (const float*)d_in[8];
  const float* b_ep     = (const float*)d_in[9];
  const float* w_vnf    = (const float*)d_in[10];
  const float* b_vnf    = (const float*)d_in[11];
  const float* attn_w1  = (const float*)d_in[12];
  const float* attn_b1  = (const float*)d_in[13];
  const float* attn_w2  = (const float*)d_in[14];
  const float* attn_b2  = (const float*)d_in[15];
  const float* attn_w3  = (const float*)d_in[16];
  const float* attn_b3  = (const float*)d_in[17];
  const float* gat_w    = (const float*)d_in[18];
  const float* att_src  = (const float*)d_in[19];
  const float* att_dst  = (const float*)d_in[20];
  const float* gat_we   = (const float*)d_in[21];
  const float* att_e    = (const float*)d_in[22];
  const float* gat_b    = (const float*)d_in[23];
  const float* ln_g     = (const float*)d_in[24];
  const float* ln_b     = (const float*)d_in[25];
  const float* venc_w1  = (const float*)d_in[26];
  const float* venc_b1  = (const float*)d_in[27];
  const float* venc_w2  = (const float*)d_in[28];
  const float* venc_b2  = (const float*)d_in[29];
  const float* lstm_wih = (const float*)d_in[30];
  const float* lstm_whh = (const float*)d_in[31];
  const float* lstm_bih = (const float*)d_in[32];
  const float* lstm_bhh = (const float*)d_in[33];
  const float* out_w1   = (const float*)d_in[34];
  const float* out_b1   = (const float*)d_in[35];
  const float* out_w2   = (const float*)d_in[36];
  const float* out_b2   = (const float*)d_in[37];
  const float* out_w3   = (const float*)d_in[38];
  const float* out_b3   = (const float*)d_in[39];

  const int N = in_sizes[0]/8;
  const int E = in_sizes[1]/2;
  const int* srcA = eidx;
  const int* dstA = eidx + E;

  const int Npad = ((N+127)/128)*128;
  const size_t atile = (size_t)(Npad/32)*64*256;
  const int nb = (N+255)/256;

  char* wp = (char*)d_ws;
  auto alloc = [&](size_t bytes)->void*{ void* p=(void*)wp; wp += (bytes+255)&~(size_t)255; return p; };
  float* xh    = (float*)alloc((size_t)N*CC*4);
  ushort* sbufH= (ushort*)alloc(atile*2);
  ushort* sbufL= (ushort*)alloc(atile*2);
  ushort* BHT  = (ushort*)alloc((size_t)LL*512*CC*2);
  ushort* BLT  = (ushort*)alloc((size_t)LL*512*CC*2);
  float* a_e   = (float*)alloc((size_t)LL*E*HH*4);
  float* asrc  = (float*)alloc((size_t)N*HH*4);
  float* adst  = (float*)alloc((size_t)N*HH*4);
  int* counts  = (int*)alloc((size_t)N*4);
  int* offsets = (int*)alloc((size_t)(N+1)*4);
  int* cursor  = (int*)alloc((size_t)N*4);
  int* elist   = (int*)alloc((size_t)E*4);
  int* bsum    = (int*)alloc((size_t)nb*4);
  float* sc    = (float*)alloc((size_t)N*4);
  float* wattS = (float*)alloc((size_t)LL*CC*HH*4);
  float* wattD = (float*)alloc((size_t)LL*CC*HH*4);
  float* wattE = (float*)alloc((size_t)LL*CC*HH*4);
  float* We    = (float*)alloc(4*CC*4);
  float* be    = (float*)alloc(CC*4);
  float* vemb  = (float*)alloc(CC*4);
  float* Wh1   = (float*)alloc(4*CC*4);
  float* bh1   = (float*)alloc(CC*4);
  float* aelin = (float*)alloc(48*4);
  float* aebias= (float*)alloc(12*4);
  float* vvec  = (float*)alloc(CC*4);
  float* lbuf  = (float*)alloc(4*CC*4);
  float* hS=lbuf; float* cS=lbuf+CC; float* qstar=lbuf+2*CC;
  float* s2s   = (float*)alloc(130*4);

  k_att_collapse<<<6,256,0,stream>>>(gat_w, att_src, wattS);
  k_att_collapse<<<6,256,0,stream>>>(gat_w, att_dst, wattD);
  k_att_collapse<<<6,256,0,stream>>>(gat_we, att_e, wattE);
  k_We<<<2,256,0,stream>>>(w_ee, w_ep, We);
  k_be_vemb<<<1,256,0,stream>>>(b_ee, w_ep, b_ep, vnf, w_vnf, b_vnf, be, vemb);
  k_h1eff<<<3,256,0,stream>>>(We, be, vemb, attn_w1, attn_b1, Wh1, bh1);
  k_aelin<<<1,64,0,stream>>>(We, be, wattE, aelin, aebias);
  k_wsplit<<<(LL*512*CC+255)/256,256,0,stream>>>(gat_w, BHT, BLT);
  k_vvec<<<1,CC,0,stream>>>(vnf, venc_w1, venc_b1, venc_w2, venc_b2, vvec);
  k_node_embed<<<(N*CC+255)/256,256,0,stream>>>(x, w_node, b_node, xh, N);

  hipMemsetAsync(counts, 0, (size_t)N*4, stream);
  k_count<<<(E+255)/256,256,0,stream>>>(dstA, counts, E);
  k_scan_blk<<<nb,256,0,stream>>>(counts, offsets, bsum, N);
  k_scan_top<<<1,1024,0,stream>>>(bsum, nb);
  k_scan_add<<<nb,256,0,stream>>>(offsets, bsum, N, E);
  hipMemsetAsync(cursor, 0, (size_t)N*4, stream);
  k_fill<<<(E+255)/256,256,0,stream>>>(dstA, offsets, cursor, elist, E);

  k_edge_attn<<<(E+63)/64,256,0,stream>>>(edge_attr, Wh1, bh1, attn_w2, attn_b2, attn_w3, attn_b3, aelin, aebias, a_e, E);

  for(int l=0;l<LL;l++){
    k_node_ad<<<(N*8+255)/256,256,0,stream>>>(xh, wattS+(size_t)l*CC*HH, wattD+(size_t)l*CC*HH, asrc, adst, N);
    k_aggregate<<<(N+3)/4,256,0,stream>>>(xh, srcA, a_e+(size_t)l*E*HH, asrc, adst, offsets, elist, sbufH, sbufL, N);
    k_gemm_ln_mfma<<<Npad/128,128,0,stream>>>(sbufH, sbufL,
                                              BHT+(size_t)l*512*CC, BLT+(size_t)l*512*CC,
                                              gat_b+(size_t)l*CC, ln_g+(size_t)l*CC, ln_b+(size_t)l*CC, xh, N);
  }

  hipMemsetAsync(lbuf, 0, 4*CC*4, stream);
  for(int it=0; it<3; ++it){
    k_lstm<<<1,512,0,stream>>>(lstm_wih, lstm_whh, lstm_bih, lstm_bhh, qstar, hS, cS);
    hipMemsetAsync(s2s, 0, 130*4, stream);
    k_scores<<<512,256,0,stream>>>(xh, hS, sc, (u32*)s2s, N);
    k_r<<<512,256,0,stream>>>(xh, sc, (u32*)s2s, s2s+2, s2s+1, N);
    k_finalize<<<1,256,0,stream>>>(hS, s2s+2, s2s+1, qstar);
  }

  k_out<<<1,256,0,stream>>>(qstar, vvec, out_w1, out_b1, out_w2, out_b2, out_w3, out_b3, (float*)d_out);
}